// Round 9
// baseline (693.740 us; speedup 1.0000x reference)
//
#include <hip/hip_runtime.h>
#include <hip/hip_bf16.h>

// ---------------------------------------------------------------------------
// GAT (3 layers) + global mean pool + linear head.
// R9: src-bucketed CSR (P=16 counting sort per node) — concurrent waves sweep
// the same ~3 MB h-window so the random gather becomes L2-resident. Pass B
// reverted to R7 form (4-deep, VGPR 28) after R8's occupancy regression.
// ---------------------------------------------------------------------------

#define LRELU(x) ((x) >= 0.f ? (x) : 0.2f * (x))

typedef unsigned short ushort8 __attribute__((ext_vector_type(8)));
typedef unsigned short ushort4v __attribute__((ext_vector_type(4)));
typedef __attribute__((ext_vector_type(8))) short bf16x8;
typedef __attribute__((ext_vector_type(4))) float f32x4;

__device__ __forceinline__ float bf2f(unsigned short u) {
    return __uint_as_float(((unsigned)u) << 16);
}
__device__ __forceinline__ unsigned short f2bf(float f) {
    __hip_bfloat16 b = __float2bfloat16(f);
    return *reinterpret_cast<unsigned short*>(&b);
}
__device__ __forceinline__ void gl_lds16(const unsigned short* g, unsigned short* l) {
    __builtin_amdgcn_global_load_lds((const __attribute__((address_space(1))) void*)g,
                                     (__attribute__((address_space(3))) void*)l, 16, 0, 0);
}

#define NBUCK 16

// ---------------- bucketed CSR build ----------------

// per-(dst,bucket) histogram
__global__ void hist16_kernel(const int* __restrict__ src, const int* __restrict__ dst,
                              int* __restrict__ bcnt, int E, int N) {
    int i = blockIdx.x * blockDim.x + threadIdx.x;
    int s, d;
    if (i < E) { s = src[i]; d = dst[i]; }
    else if (i < E + N) { s = i - E; d = s; }
    else return;
    int b = (s * NBUCK) / N;
    atomicAdd(&bcnt[d * NBUCK + b], 1);
}

__global__ void node_deg_kernel(const int* __restrict__ bcnt, int* __restrict__ deg, int N) {
    int n = blockIdx.x * blockDim.x + threadIdx.x;
    if (n >= N) return;
    int s = 0;
#pragma unroll
    for (int b = 0; b < NBUCK; b++) s += bcnt[n * NBUCK + b];
    deg[n] = s;
}

__global__ void scan_kernel(const int* __restrict__ deg, int* __restrict__ rowptr,
                            int n) {
    __shared__ int partial[1024];
    const int tid = threadIdx.x;
    const int chunk = (n + 1023) / 1024;
    const int start = min(tid * chunk, n);
    const int end = min(start + chunk, n);
    int s = 0;
    for (int i = start; i < end; i++) s += deg[i];
    partial[tid] = s;
    __syncthreads();
    for (int o = 1; o < 1024; o <<= 1) {
        int v = (tid >= o) ? partial[tid - o] : 0;
        __syncthreads();
        partial[tid] += v;
        __syncthreads();
    }
    int run = (tid == 0) ? 0 : partial[tid - 1];
    for (int i = start; i < end; i++) { rowptr[i] = run; run += deg[i]; }
    if (tid == 0) rowptr[n] = partial[1023];
}

__global__ void bstart_fill_kernel(const int* __restrict__ bcnt, const int* __restrict__ rowptr,
                                   int* __restrict__ bstart, int N) {
    int n = blockIdx.x * blockDim.x + threadIdx.x;
    if (n >= N) return;
    int base = rowptr[n];
#pragma unroll
    for (int b = 0; b < NBUCK; b++) {
        bstart[n * NBUCK + b] = base;
        base += bcnt[n * NBUCK + b];
    }
}

// Binned by dst (write locality); position from per-(dst,bucket) counter ->
// each node's segment ends up sorted by src bucket.
__global__ void scatter_col_binned(const int* __restrict__ src, const int* __restrict__ dst,
                                   int* __restrict__ bstart, int* __restrict__ col,
                                   int E, int N, int lo, int hi) {
    int i = blockIdx.x * blockDim.x + threadIdx.x;
    int s, d;
    if (i < E) {
        d = dst[i];
        if (d < lo || d >= hi) return;
        s = src[i];
    } else if (i < E + N) {
        d = i - E;
        if (d < lo || d >= hi) return;
        s = d;
    } else return;
    int b = (s * NBUCK) / N;
    int pos = atomicAdd(&bstart[d * NBUCK + b], 1);
    col[pos] = s;
}

__global__ void expand_dst_kernel(const int* __restrict__ rowptr, int* __restrict__ dstA,
                                  int N) {
    int n = blockIdx.x * blockDim.x + threadIdx.x;
    if (n >= N) return;
    int r0 = rowptr[n];
    int r1 = rowptr[n + 1];
    for (int p = r0; p < r1; p++) dstA[p] = n;
}

__global__ void gstart_kernel(const int* __restrict__ batch, int* __restrict__ gstart,
                              int N, int G) {
    int g = blockIdx.x * blockDim.x + threadIdx.x;
    if (g > G) return;
    int lo = 0, hi = N;
    while (lo < hi) { int mid = (lo + hi) >> 1; if (batch[mid] < g) lo = mid + 1; else hi = mid; }
    gstart[g] = lo;
}

// ---------------- f32 -> bf16 hi/lo split kernels ----------------

__global__ void split_plain_kernel(const float* __restrict__ X, unsigned short* __restrict__ h,
                                   unsigned short* __restrict__ l, int n) {
    int i = blockIdx.x * blockDim.x + threadIdx.x;
    if (i >= n) return;
    float v = X[i];
    unsigned short hb = f2bf(v);
    h[i] = hb;
    l[i] = f2bf(v - bf2f(hb));
}

__global__ void splitT_kernel(const float* __restrict__ W, unsigned short* __restrict__ th,
                              unsigned short* __restrict__ tl, int K, int N) {
    int i = blockIdx.x * blockDim.x + threadIdx.x;
    if (i >= N * K) return;
    int n = i / K, k = i - n * K;
    float v = W[(size_t)k * N + n];
    unsigned short hb = f2bf(v);
    th[i] = hb;
    tl[i] = f2bf(v - bf2f(hb));
}

// ---------------- MFMA split-bf16 GEMM, global_load_lds staging ----------------

template <int BM, int BN, int WM, int WN>
__global__ __launch_bounds__(256)
void gemm_mfma_v2(const unsigned short* __restrict__ Ah, const unsigned short* __restrict__ Al,
                  const unsigned short* __restrict__ Bth, const unsigned short* __restrict__ Btl,
                  unsigned short* __restrict__ Cc, int M, int N, int K) {
    constexpr int BK = 32;
    constexpr int MT = WM / 16, NT = WN / 16;
    constexpr int NWX = BN / WN;
    __shared__ __attribute__((aligned(16))) unsigned short Ha[BM][BK];
    __shared__ __attribute__((aligned(16))) unsigned short La[BM][BK];
    __shared__ __attribute__((aligned(16))) unsigned short Hb[BN][BK];
    __shared__ __attribute__((aligned(16))) unsigned short Lb[BN][BK];
    const int tid = threadIdx.x;
    const int lane = tid & 63;
    const int wave = tid >> 6;
    const int wx = wave % NWX, wy = wave / NWX;
    const int by = blockIdx.y * BM;
    const int bx = blockIdx.x * BN;
    const int r16 = lane & 15, kg = lane >> 4;
    const int srow = lane >> 2, sslot = lane & 3;

    f32x4 acc[MT][NT];
#pragma unroll
    for (int i = 0; i < MT; i++)
#pragma unroll
        for (int j = 0; j < NT; j++) acc[i][j] = (f32x4){0.f, 0.f, 0.f, 0.f};

    for (int k0 = 0; k0 < K; k0 += BK) {
        for (int t = wave; t < BM / 16; t += 4) {
            int gm = by + t * 16 + srow;
            if (gm >= M) gm = M - 1;
            const size_t goff = (size_t)gm * K + k0 + sslot * 8;
            gl_lds16(Ah + goff, &Ha[t * 16][0]);
            gl_lds16(Al + goff, &La[t * 16][0]);
        }
        for (int t = wave; t < BN / 16; t += 4) {
            int gn = bx + t * 16 + srow;
            const size_t goff = (size_t)gn * K + k0 + sslot * 8;
            gl_lds16(Bth + goff, &Hb[t * 16][0]);
            gl_lds16(Btl + goff, &Lb[t * 16][0]);
        }
        __syncthreads();
        bf16x8 bh[NT], bl[NT];
#pragma unroll
        for (int j = 0; j < NT; j++) {
            bh[j] = *(const bf16x8*)&Hb[wx * WN + j * 16 + r16][kg * 8];
            bl[j] = *(const bf16x8*)&Lb[wx * WN + j * 16 + r16][kg * 8];
        }
#pragma unroll
        for (int i = 0; i < MT; i++) {
            bf16x8 ah = *(const bf16x8*)&Ha[wy * WM + i * 16 + r16][kg * 8];
            bf16x8 al2 = *(const bf16x8*)&La[wy * WM + i * 16 + r16][kg * 8];
#pragma unroll
            for (int j = 0; j < NT; j++) {
                acc[i][j] = __builtin_amdgcn_mfma_f32_16x16x32_bf16(ah, bh[j], acc[i][j], 0, 0, 0);
                acc[i][j] = __builtin_amdgcn_mfma_f32_16x16x32_bf16(ah, bl[j], acc[i][j], 0, 0, 0);
                acc[i][j] = __builtin_amdgcn_mfma_f32_16x16x32_bf16(al2, bh[j], acc[i][j], 0, 0, 0);
            }
        }
        __syncthreads();
    }
#pragma unroll
    for (int i = 0; i < MT; i++) {
#pragma unroll
        for (int r = 0; r < 4; r++) {
            int gm = by + wy * WM + i * 16 + kg * 4 + r;
            if (gm >= M) continue;
#pragma unroll
            for (int j = 0; j < NT; j++) {
                int gn = bx + wx * WN + j * 16 + r16;
                Cc[(size_t)gm * N + gn] = f2bf(acc[i][j][r]);
            }
        }
    }
}

// ---------------- per-node attention logits (bf16 h, 16B loads) ----------------

template <int H, int C>
__global__ void al_bf16(const unsigned short* __restrict__ hfeat, const float* __restrict__ a_src,
                        const float* __restrict__ a_dst, float* __restrict__ als,
                        float* __restrict__ ald, int N) {
    int i = blockIdx.x * blockDim.x + threadIdx.x;
    if (i >= N * H) return;
    int n = i / H, h = i % H;
    const unsigned short* hp = hfeat + (size_t)n * H * C + h * C;
    float s1 = 0.f, s2 = 0.f;
    for (int c0 = 0; c0 < C; c0 += 8) {
        ushort8 v = *(const ushort8*)(hp + c0);
#pragma unroll
        for (int k = 0; k < 8; k++) {
            float f = bf2f(v[k]);
            s1 += f * a_src[h * C + c0 + k];
            s2 += f * a_dst[h * C + c0 + k];
        }
    }
    als[i] = s1;
    ald[i] = s2;
}

// ---------------- per-edge softmax numerator ----------------

__global__ void edge_w_pair(const float* __restrict__ als, const float* __restrict__ ald,
                            const int* __restrict__ col, const int* __restrict__ dstA,
                            unsigned int* __restrict__ wts2, int Etot) {
    int i = blockIdx.x * blockDim.x + threadIdx.x;
    if (i >= Etot * 4) return;
    int pos = i >> 2, hp = i & 3;
    int s = col[pos], d = dstA[pos];
    float2 a = *(const float2*)&als[(size_t)s * 8 + hp * 2];
    float2 b = *(const float2*)&ald[(size_t)d * 8 + hp * 2];
    float e0 = a.x + b.x; e0 = LRELU(e0);
    float e1 = a.y + b.y; e1 = LRELU(e1);
    unsigned lo = f2bf(__expf(e0));
    unsigned hi = f2bf(__expf(e1));
    wts2[i] = lo | (hi << 16);
}

__global__ void edge_w_h1(const float* __restrict__ als, const float* __restrict__ ald,
                          const int* __restrict__ col, const int* __restrict__ dstA,
                          unsigned short* __restrict__ wts, int Etot) {
    int i = blockIdx.x * blockDim.x + threadIdx.x;
    if (i >= Etot) return;
    int s = col[i], d = dstA[i];
    float e = als[s] + ald[d];
    e = LRELU(e);
    wts[i] = f2bf(__expf(e));
}

// ---------------- H=8 aggregate: wave-per-node (R7 pass B) ----------------

__global__ __launch_bounds__(256)
void gat_agg_w8(const unsigned short* __restrict__ hfeat,
                const unsigned short* __restrict__ wts,   // [pos][8] bf16 bits
                const int* __restrict__ rowptr,           // standard convention
                const int* __restrict__ col,
                const float* __restrict__ bias,
                unsigned short* __restrict__ outH, unsigned short* __restrict__ outL,
                int N) {
    constexpr int CAP = 128;
    const int wid = threadIdx.x >> 6;
    const int lane = threadIdx.x & 63;
    const int n = blockIdx.x * 4 + wid;
    __shared__ float se_all[4][CAP * 8];
    __shared__ int scol_all[4][CAP];
    if (n >= N) return;
    float* se = se_all[wid];
    int* scol = scol_all[wid];

    const int r0 = rowptr[n];
    const int deg = rowptr[n + 1] - r0;
    const int dh8 = deg * 8;
    const size_t wbase = (size_t)r0 * 8;
    const int dcap = min(deg, CAP);

    // stage col -> LDS (coalesced)
    for (int j = lane; j < dcap; j += 64) scol[j] = col[r0 + j];

    // ---- pass A: weights -> se + per-head sums in registers ----
    float p0 = 0.f, p1 = 0.f, p2 = 0.f, p3 = 0.f, p4 = 0.f, p5 = 0.f, p6 = 0.f, p7 = 0.f;
    for (int base = 0; base < dh8; base += 512) {
        int idx = base + lane * 8;
        if (idx < dh8) {
            ushort8 v = *(const ushort8*)&wts[wbase + idx];
            float f0 = bf2f(v[0]), f1 = bf2f(v[1]), f2 = bf2f(v[2]), f3 = bf2f(v[3]);
            float f4 = bf2f(v[4]), f5 = bf2f(v[5]), f6 = bf2f(v[6]), f7 = bf2f(v[7]);
            p0 += f0; p1 += f1; p2 += f2; p3 += f3;
            p4 += f4; p5 += f5; p6 += f6; p7 += f7;
            if (idx < CAP * 8) {
                *(float4*)&se[idx] = (float4){f0, f1, f2, f3};
                *(float4*)&se[idx + 4] = (float4){f4, f5, f6, f7};
            }
        }
    }
#pragma unroll
    for (int m = 1; m < 64; m <<= 1) {
        p0 += __shfl_xor(p0, m); p1 += __shfl_xor(p1, m);
        p2 += __shfl_xor(p2, m); p3 += __shfl_xor(p3, m);
        p4 += __shfl_xor(p4, m); p5 += __shfl_xor(p5, m);
        p6 += __shfl_xor(p6, m); p7 += __shfl_xor(p7, m);
    }
    const int q = lane >> 3;
    float S = (q == 0) ? p0 : (q == 1) ? p1 : (q == 2) ? p2 : (q == 3) ? p3
            : (q == 4) ? p4 : (q == 5) ? p5 : (q == 6) ? p6 : p7;
    const float sinv = 1.0f / S;

    // ---- pass B: 4-deep gather (R7 form) ----
    const int cb = lane * 4;
    float a0 = 0.f, a1 = 0.f, a2 = 0.f, a3 = 0.f;
    int j = 0;
    for (; j + 3 < dcap; j += 4) {
        int s0 = __builtin_amdgcn_readfirstlane(scol[j]);
        int s1 = __builtin_amdgcn_readfirstlane(scol[j + 1]);
        int s2 = __builtin_amdgcn_readfirstlane(scol[j + 2]);
        int s3 = __builtin_amdgcn_readfirstlane(scol[j + 3]);
        ushort4v v0 = *(const ushort4v*)(hfeat + (size_t)s0 * 256 + cb);
        ushort4v v1 = *(const ushort4v*)(hfeat + (size_t)s1 * 256 + cb);
        ushort4v v2 = *(const ushort4v*)(hfeat + (size_t)s2 * 256 + cb);
        ushort4v v3 = *(const ushort4v*)(hfeat + (size_t)s3 * 256 + cb);
        float w0 = se[j * 8 + q];
        float w1 = se[j * 8 + 8 + q];
        float w2 = se[j * 8 + 16 + q];
        float w3 = se[j * 8 + 24 + q];
        a0 += bf2f(v0[0]) * w0; a1 += bf2f(v0[1]) * w0; a2 += bf2f(v0[2]) * w0; a3 += bf2f(v0[3]) * w0;
        a0 += bf2f(v1[0]) * w1; a1 += bf2f(v1[1]) * w1; a2 += bf2f(v1[2]) * w1; a3 += bf2f(v1[3]) * w1;
        a0 += bf2f(v2[0]) * w2; a1 += bf2f(v2[1]) * w2; a2 += bf2f(v2[2]) * w2; a3 += bf2f(v2[3]) * w2;
        a0 += bf2f(v3[0]) * w3; a1 += bf2f(v3[1]) * w3; a2 += bf2f(v3[2]) * w3; a3 += bf2f(v3[3]) * w3;
    }
    for (; j < dcap; j++) {
        int s0 = __builtin_amdgcn_readfirstlane(scol[j]);
        ushort4v v0 = *(const ushort4v*)(hfeat + (size_t)s0 * 256 + cb);
        float w0 = se[j * 8 + q];
        a0 += bf2f(v0[0]) * w0; a1 += bf2f(v0[1]) * w0; a2 += bf2f(v0[2]) * w0; a3 += bf2f(v0[3]) * w0;
    }
    for (; j < deg; j++) {                   // deg > CAP fallback (essentially never)
        int s0 = col[r0 + j];
        float w0 = bf2f(wts[wbase + (size_t)j * 8 + q]);
        ushort4v v0 = *(const ushort4v*)(hfeat + (size_t)s0 * 256 + cb);
        a0 += bf2f(v0[0]) * w0; a1 += bf2f(v0[1]) * w0; a2 += bf2f(v0[2]) * w0; a3 += bf2f(v0[3]) * w0;
    }

    // ---- epilogue: normalize + bias + relu + hi/lo split store ----
    float4 b4 = *(const float4*)&bias[cb];
    float o0 = fmaxf(a0 * sinv + b4.x, 0.f);
    float o1 = fmaxf(a1 * sinv + b4.y, 0.f);
    float o2 = fmaxf(a2 * sinv + b4.z, 0.f);
    float o3 = fmaxf(a3 * sinv + b4.w, 0.f);
    unsigned short h0 = f2bf(o0), h1 = f2bf(o1), h2 = f2bf(o2), h3 = f2bf(o3);
    const size_t ob = (size_t)n * 256 + cb;
    *(ushort4v*)&outH[ob] = (ushort4v){h0, h1, h2, h3};
    *(ushort4v*)&outL[ob] = (ushort4v){f2bf(o0 - bf2f(h0)), f2bf(o1 - bf2f(h1)),
                                       f2bf(o2 - bf2f(h2)), f2bf(o3 - bf2f(h3))};
}

// ---------------- H=1 aggregate: wave-per-node, 8 lanes/edge ----------------

__global__ __launch_bounds__(256)
void gat_agg_h1w(const unsigned short* __restrict__ hfeat,
                 const unsigned short* __restrict__ wts,
                 const int* __restrict__ rowptr, const int* __restrict__ col,
                 const float* __restrict__ bias, float* __restrict__ out, int N) {
    constexpr int CAP = 256;
    const int wid = threadIdx.x >> 6;
    const int lane = threadIdx.x & 63;
    const int n = blockIdx.x * 4 + wid;
    __shared__ float sw_all[4][CAP];
    __shared__ int scol_all[4][CAP];
    if (n >= N) return;
    float* sw = sw_all[wid];
    int* scol = scol_all[wid];

    const int r0 = rowptr[n];
    const int deg = rowptr[n + 1] - r0;
    const int dcap = min(deg, CAP);

    float lsum = 0.f;
    for (int idx = lane; idx < deg; idx += 64) {
        float v = bf2f(wts[r0 + idx]);
        if (idx < CAP) { sw[idx] = v; scol[idx] = col[r0 + idx]; }
        lsum += v;
    }
#pragma unroll
    for (int m = 1; m < 64; m <<= 1) lsum += __shfl_xor(lsum, m);
    const float sinv = 1.0f / lsum;

    const int slot = lane >> 3, ch = lane & 7;
    float a0 = 0.f, a1 = 0.f, a2 = 0.f, a3 = 0.f;
    for (int j = 0; j < dcap; j += 8) {
        int e = j + slot;
        int ec = min(e, dcap - 1);
        int s = scol[ec];
        float w = (e < dcap) ? sw[ec] : 0.f;
        ushort4v v = *(const ushort4v*)(hfeat + (size_t)s * 32 + ch * 4);
        a0 += bf2f(v[0]) * w; a1 += bf2f(v[1]) * w;
        a2 += bf2f(v[2]) * w; a3 += bf2f(v[3]) * w;
    }
    for (int j = CAP; j < deg; j += 8) {
        int e = j + slot;
        int ec = min(e, deg - 1);
        int s = col[r0 + ec];
        float w = (e < deg) ? bf2f(wts[r0 + ec]) : 0.f;
        ushort4v v = *(const ushort4v*)(hfeat + (size_t)s * 32 + ch * 4);
        a0 += bf2f(v[0]) * w; a1 += bf2f(v[1]) * w;
        a2 += bf2f(v[2]) * w; a3 += bf2f(v[3]) * w;
    }
#pragma unroll
    for (int m = 8; m < 64; m <<= 1) {
        a0 += __shfl_xor(a0, m);
        a1 += __shfl_xor(a1, m);
        a2 += __shfl_xor(a2, m);
        a3 += __shfl_xor(a3, m);
    }
    if (slot == 0) {
        float4 b4 = *(const float4*)&bias[ch * 4];
        float4 o;
        o.x = a0 * sinv + b4.x;
        o.y = a1 * sinv + b4.y;
        o.z = a2 * sinv + b4.z;
        o.w = a3 * sinv + b4.w;
        *(float4*)&out[(size_t)n * 32 + ch * 4] = o;
    }
}

// ---------------- fused pool + head (sorted batch, no atomics) ----------------

__global__ __launch_bounds__(256)
void pool_final_kernel(const float* __restrict__ h, const int* __restrict__ gstart,
                       const float* __restrict__ lin_w, const float* __restrict__ lin_b,
                       float* __restrict__ out) {
    const int g = blockIdx.x;
    const int tid = threadIdx.x;
    const int n0 = gstart[g], n1 = gstart[g + 1];
    const int r = tid >> 5, c = tid & 31;
    __shared__ float pp[4][32];
    __shared__ float pm[32];
    float acc = 0.f;
    for (int n = n0 + r; n < n1; n += 8) acc += h[(size_t)n * 32 + c];
    acc += __shfl_xor(acc, 32);
    if ((tid & 63) < 32) pp[tid >> 6][c] = acc;
    __syncthreads();
    if (tid < 32) {
        float s = pp[0][tid] + pp[1][tid] + pp[2][tid] + pp[3][tid];
        pm[tid] = s / fmaxf((float)(n1 - n0), 1.f);
    }
    __syncthreads();
    if (tid < 64) {
        float a = lin_b[tid];
#pragma unroll 8
        for (int cc = 0; cc < 32; cc++) a += pm[cc] * lin_w[cc * 64 + tid];
        out[(size_t)g * 64 + tid] = a;
    }
}

// ---------------- launch ----------------

extern "C" void kernel_launch(void* const* d_in, const int* in_sizes, int n_in,
                              void* d_out, int out_size, void* d_ws, size_t ws_size,
                              hipStream_t stream) {
    const float* x     = (const float*)d_in[0];
    const int*   ei    = (const int*)d_in[1];
    const int*   batch = (const int*)d_in[2];
    const float* W0    = (const float*)d_in[3];
    const float* a_s0  = (const float*)d_in[4];
    const float* a_d0  = (const float*)d_in[5];
    const float* b0    = (const float*)d_in[6];
    const float* W1    = (const float*)d_in[7];
    const float* a_s1  = (const float*)d_in[8];
    const float* a_d1  = (const float*)d_in[9];
    const float* b1    = (const float*)d_in[10];
    const float* W2    = (const float*)d_in[11];
    const float* a_s2  = (const float*)d_in[12];
    const float* a_d2  = (const float*)d_in[13];
    const float* b2    = (const float*)d_in[14];
    const float* lin_w = (const float*)d_in[15];
    const float* lin_b = (const float*)d_in[16];

    const int N = in_sizes[0] / 128;   // 50000
    const int E = in_sizes[1] / 2;     // 1600000
    const int G = 256;
    const int Etot = E + N;
    const int* src = ei;
    const int* dst = ei + E;

    char* w = (char*)d_ws;
    size_t off = 0;
    auto alloc = [&](size_t bytes) -> void* {
        void* p = (void*)(w + off);
        off += (bytes + 255) & ~(size_t)255;
        return p;
    };
    int* bcnt   = (int*)alloc((size_t)N * NBUCK * 4);
    int* bstart = (int*)alloc((size_t)N * NBUCK * 4);
    int* deg    = (int*)alloc((size_t)N * 4);
    int* rowptr = (int*)alloc((size_t)(N + 1) * 4);
    int* colA   = (int*)alloc((size_t)Etot * 4);
    int* dstA   = (int*)alloc((size_t)Etot * 4);
    int* gstart = (int*)alloc((size_t)(G + 1) * 4);
    float* als  = (float*)alloc((size_t)N * 8 * 4);
    float* ald  = (float*)alloc((size_t)N * 8 * 4);
    unsigned short* hb  = (unsigned short*)alloc((size_t)N * 256 * 2);
    unsigned short* wts = (unsigned short*)alloc((size_t)Etot * 8 * 2);
    unsigned short* g0h = (unsigned short*)alloc((size_t)N * 256 * 2);
    unsigned short* g0l = (unsigned short*)alloc((size_t)N * 256 * 2);
    float* out2 = (float*)alloc((size_t)N * 32 * 4);
    unsigned short* w0h = (unsigned short*)alloc((size_t)128 * 256 * 2);
    unsigned short* w0l = (unsigned short*)alloc((size_t)128 * 256 * 2);
    unsigned short* w1h = (unsigned short*)alloc((size_t)256 * 256 * 2);
    unsigned short* w1l = (unsigned short*)alloc((size_t)256 * 256 * 2);
    unsigned short* w2h = (unsigned short*)alloc((size_t)256 * 32 * 2);
    unsigned short* w2l = (unsigned short*)alloc((size_t)256 * 32 * 2);
    unsigned short* xh = g0h;
    unsigned short* xl = g0h + (size_t)N * 128;

    hipMemsetAsync(bcnt, 0, (size_t)N * NBUCK * 4, stream);

    // bucketed CSR build
    hist16_kernel<<<(Etot + 255) / 256, 256, 0, stream>>>(src, dst, bcnt, E, N);
    node_deg_kernel<<<(N + 255) / 256, 256, 0, stream>>>(bcnt, deg, N);
    scan_kernel<<<1, 1024, 0, stream>>>(deg, rowptr, N);
    bstart_fill_kernel<<<(N + 255) / 256, 256, 0, stream>>>(bcnt, rowptr, bstart, N);
    for (int p = 0; p < 2; p++) {
        int lo = (int)((size_t)N * p / 2);
        int hi = (int)((size_t)N * (p + 1) / 2);
        scatter_col_binned<<<(Etot + 255) / 256, 256, 0, stream>>>(src, dst, bstart, colA, E, N, lo, hi);
    }
    expand_dst_kernel<<<(N + 255) / 256, 256, 0, stream>>>(rowptr, dstA, N);
    gstart_kernel<<<2, 256, 0, stream>>>(batch, gstart, N, G);

    split_plain_kernel<<<(N * 128 + 255) / 256, 256, 0, stream>>>(x, xh, xl, N * 128);
    splitT_kernel<<<(128 * 256 + 255) / 256, 256, 0, stream>>>(W0, w0h, w0l, 128, 256);
    splitT_kernel<<<(256 * 256 + 255) / 256, 256, 0, stream>>>(W1, w1h, w1l, 256, 256);
    splitT_kernel<<<(256 * 32 + 255) / 256, 256, 0, stream>>>(W2, w2h, w2l, 256, 32);

    const int MB = (N + 127) / 128;

    // layer 0: K=128
    gemm_mfma_v2<128, 128, 64, 64><<<dim3(2, MB), 256, 0, stream>>>(xh, xl, w0h, w0l, hb, N, 256, 128);
    al_bf16<8, 32><<<(N * 8 + 255) / 256, 256, 0, stream>>>(hb, a_s0, a_d0, als, ald, N);
    edge_w_pair<<<((size_t)Etot * 4 + 255) / 256, 256, 0, stream>>>(als, ald, colA, dstA, (unsigned int*)wts, Etot);
    gat_agg_w8<<<(N + 3) / 4, 256, 0, stream>>>(hb, wts, rowptr, colA, b0, g0h, g0l, N);

    // layer 1: K=256
    gemm_mfma_v2<128, 128, 64, 64><<<dim3(2, MB), 256, 0, stream>>>(g0h, g0l, w1h, w1l, hb, N, 256, 256);
    al_bf16<8, 32><<<(N * 8 + 255) / 256, 256, 0, stream>>>(hb, a_s1, a_d1, als, ald, N);
    edge_w_pair<<<((size_t)Etot * 4 + 255) / 256, 256, 0, stream>>>(als, ald, colA, dstA, (unsigned int*)wts, Etot);
    gat_agg_w8<<<(N + 3) / 4, 256, 0, stream>>>(hb, wts, rowptr, colA, b1, g0h, g0l, N);

    // layer 2: heads=1, C=32, K=256
    gemm_mfma_v2<128, 32, 32, 32><<<dim3(1, MB), 256, 0, stream>>>(g0h, g0l, w2h, w2l, hb, N, 32, 256);
    al_bf16<1, 32><<<(N + 255) / 256, 256, 0, stream>>>(hb, a_s2, a_d2, als, ald, N);
    edge_w_h1<<<(Etot + 255) / 256, 256, 0, stream>>>(als, ald, colA, dstA, wts, Etot);
    gat_agg_h1w<<<(N + 3) / 4, 256, 0, stream>>>(hb, wts, rowptr, colA, b2, out2, N);

    // fused pool + head
    pool_final_kernel<<<G, 256, 0, stream>>>(out2, gstart, lin_w, lin_b, (float*)d_out);
}

// Round 10
// 668.971 us; speedup vs baseline: 1.0370x; 1.0370x over previous
//
#include <hip/hip_runtime.h>
#include <hip/hip_bf16.h>

// ---------------------------------------------------------------------------
// GAT (3 layers) + global mean pool + linear head.
// R10: edge-weight pipeline deleted — agg computes exp(lrelu(als[s]+ald[n]))
// in-kernel (als/ald are 1.6 MB, L2-resident). Removes edge_w kernels,
// expand_dst, dstA/wts buffers. Build reverted to simple 2-pass shifted
// scatter (R9 bucketing was null).
// ---------------------------------------------------------------------------

#define LRELU(x) ((x) >= 0.f ? (x) : 0.2f * (x))

typedef unsigned short ushort8 __attribute__((ext_vector_type(8)));
typedef unsigned short ushort4v __attribute__((ext_vector_type(4)));
typedef __attribute__((ext_vector_type(8))) short bf16x8;
typedef __attribute__((ext_vector_type(4))) float f32x4;

__device__ __forceinline__ float bf2f(unsigned short u) {
    return __uint_as_float(((unsigned)u) << 16);
}
__device__ __forceinline__ unsigned short f2bf(float f) {
    __hip_bfloat16 b = __float2bfloat16(f);
    return *reinterpret_cast<unsigned short*>(&b);
}
__device__ __forceinline__ void gl_lds16(const unsigned short* g, unsigned short* l) {
    __builtin_amdgcn_global_load_lds((const __attribute__((address_space(1))) void*)g,
                                     (__attribute__((address_space(3))) void*)l, 16, 0, 0);
}

// ---------------- CSR build ----------------

__global__ void deg_kernel(const int* __restrict__ dst, int* __restrict__ deg,
                           int E, int N) {
    int i = blockIdx.x * blockDim.x + threadIdx.x;
    if (i < E) atomicAdd(&deg[dst[i]], 1);
    else if (i < E + N) atomicAdd(&deg[i - E], 1);   // self loop
}

__global__ void scan_kernel(const int* __restrict__ deg, int* __restrict__ rowptr,
                            int n) {
    __shared__ int partial[1024];
    const int tid = threadIdx.x;
    const int chunk = (n + 1023) / 1024;
    const int start = min(tid * chunk, n);
    const int end = min(start + chunk, n);
    int s = 0;
    for (int i = start; i < end; i++) s += deg[i];
    partial[tid] = s;
    __syncthreads();
    for (int o = 1; o < 1024; o <<= 1) {
        int v = (tid >= o) ? partial[tid - o] : 0;
        __syncthreads();
        partial[tid] += v;
        __syncthreads();
    }
    int run = (tid == 0) ? 0 : partial[tid - 1];
    for (int i = start; i < end; i++) { rowptr[i] = run; run += deg[i]; }
    if (tid == 0) rowptr[n] = partial[1023];
}

// Binned scatter on rowptr itself: after both passes rowptr[n] = END of
// segment n (start = rowptr[n-1], 0 for n=0) — shifted convention.
__global__ void scatter_col_binned(const int* __restrict__ src, const int* __restrict__ dst,
                                   int* __restrict__ rowptr, int* __restrict__ col,
                                   int E, int N, int lo, int hi) {
    int i = blockIdx.x * blockDim.x + threadIdx.x;
    if (i < E) {
        int d = dst[i];
        if (d < lo || d >= hi) return;
        int pos = atomicAdd(&rowptr[d], 1);
        col[pos] = src[i];
    } else if (i < E + N) {
        int d = i - E;
        if (d < lo || d >= hi) return;
        int pos = atomicAdd(&rowptr[d], 1);
        col[pos] = d;
    }
}

__global__ void gstart_kernel(const int* __restrict__ batch, int* __restrict__ gstart,
                              int N, int G) {
    int g = blockIdx.x * blockDim.x + threadIdx.x;
    if (g > G) return;
    int lo = 0, hi = N;
    while (lo < hi) { int mid = (lo + hi) >> 1; if (batch[mid] < g) lo = mid + 1; else hi = mid; }
    gstart[g] = lo;
}

// ---------------- f32 -> bf16 hi/lo split kernels ----------------

__global__ void split_plain_kernel(const float* __restrict__ X, unsigned short* __restrict__ h,
                                   unsigned short* __restrict__ l, int n) {
    int i = blockIdx.x * blockDim.x + threadIdx.x;
    if (i >= n) return;
    float v = X[i];
    unsigned short hb = f2bf(v);
    h[i] = hb;
    l[i] = f2bf(v - bf2f(hb));
}

__global__ void splitT_kernel(const float* __restrict__ W, unsigned short* __restrict__ th,
                              unsigned short* __restrict__ tl, int K, int N) {
    int i = blockIdx.x * blockDim.x + threadIdx.x;
    if (i >= N * K) return;
    int n = i / K, k = i - n * K;
    float v = W[(size_t)k * N + n];
    unsigned short hb = f2bf(v);
    th[i] = hb;
    tl[i] = f2bf(v - bf2f(hb));
}

// ---------------- MFMA split-bf16 GEMM, global_load_lds staging ----------------

template <int BM, int BN, int WM, int WN>
__global__ __launch_bounds__(256)
void gemm_mfma_v2(const unsigned short* __restrict__ Ah, const unsigned short* __restrict__ Al,
                  const unsigned short* __restrict__ Bth, const unsigned short* __restrict__ Btl,
                  unsigned short* __restrict__ Cc, int M, int N, int K) {
    constexpr int BK = 32;
    constexpr int MT = WM / 16, NT = WN / 16;
    constexpr int NWX = BN / WN;
    __shared__ __attribute__((aligned(16))) unsigned short Ha[BM][BK];
    __shared__ __attribute__((aligned(16))) unsigned short La[BM][BK];
    __shared__ __attribute__((aligned(16))) unsigned short Hb[BN][BK];
    __shared__ __attribute__((aligned(16))) unsigned short Lb[BN][BK];
    const int tid = threadIdx.x;
    const int lane = tid & 63;
    const int wave = tid >> 6;
    const int wx = wave % NWX, wy = wave / NWX;
    const int by = blockIdx.y * BM;
    const int bx = blockIdx.x * BN;
    const int r16 = lane & 15, kg = lane >> 4;
    const int srow = lane >> 2, sslot = lane & 3;

    f32x4 acc[MT][NT];
#pragma unroll
    for (int i = 0; i < MT; i++)
#pragma unroll
        for (int j = 0; j < NT; j++) acc[i][j] = (f32x4){0.f, 0.f, 0.f, 0.f};

    for (int k0 = 0; k0 < K; k0 += BK) {
        for (int t = wave; t < BM / 16; t += 4) {
            int gm = by + t * 16 + srow;
            if (gm >= M) gm = M - 1;
            const size_t goff = (size_t)gm * K + k0 + sslot * 8;
            gl_lds16(Ah + goff, &Ha[t * 16][0]);
            gl_lds16(Al + goff, &La[t * 16][0]);
        }
        for (int t = wave; t < BN / 16; t += 4) {
            int gn = bx + t * 16 + srow;
            const size_t goff = (size_t)gn * K + k0 + sslot * 8;
            gl_lds16(Bth + goff, &Hb[t * 16][0]);
            gl_lds16(Btl + goff, &Lb[t * 16][0]);
        }
        __syncthreads();
        bf16x8 bh[NT], bl[NT];
#pragma unroll
        for (int j = 0; j < NT; j++) {
            bh[j] = *(const bf16x8*)&Hb[wx * WN + j * 16 + r16][kg * 8];
            bl[j] = *(const bf16x8*)&Lb[wx * WN + j * 16 + r16][kg * 8];
        }
#pragma unroll
        for (int i = 0; i < MT; i++) {
            bf16x8 ah = *(const bf16x8*)&Ha[wy * WM + i * 16 + r16][kg * 8];
            bf16x8 al2 = *(const bf16x8*)&La[wy * WM + i * 16 + r16][kg * 8];
#pragma unroll
            for (int j = 0; j < NT; j++) {
                acc[i][j] = __builtin_amdgcn_mfma_f32_16x16x32_bf16(ah, bh[j], acc[i][j], 0, 0, 0);
                acc[i][j] = __builtin_amdgcn_mfma_f32_16x16x32_bf16(ah, bl[j], acc[i][j], 0, 0, 0);
                acc[i][j] = __builtin_amdgcn_mfma_f32_16x16x32_bf16(al2, bh[j], acc[i][j], 0, 0, 0);
            }
        }
        __syncthreads();
    }
#pragma unroll
    for (int i = 0; i < MT; i++) {
#pragma unroll
        for (int r = 0; r < 4; r++) {
            int gm = by + wy * WM + i * 16 + kg * 4 + r;
            if (gm >= M) continue;
#pragma unroll
            for (int j = 0; j < NT; j++) {
                int gn = bx + wx * WN + j * 16 + r16;
                Cc[(size_t)gm * N + gn] = f2bf(acc[i][j][r]);
            }
        }
    }
}

// ---------------- per-node attention logits (bf16 h, 16B loads) ----------------

template <int H, int C>
__global__ void al_bf16(const unsigned short* __restrict__ hfeat, const float* __restrict__ a_src,
                        const float* __restrict__ a_dst, float* __restrict__ als,
                        float* __restrict__ ald, int N) {
    int i = blockIdx.x * blockDim.x + threadIdx.x;
    if (i >= N * H) return;
    int n = i / H, h = i % H;
    const unsigned short* hp = hfeat + (size_t)n * H * C + h * C;
    float s1 = 0.f, s2 = 0.f;
    for (int c0 = 0; c0 < C; c0 += 8) {
        ushort8 v = *(const ushort8*)(hp + c0);
#pragma unroll
        for (int k = 0; k < 8; k++) {
            float f = bf2f(v[k]);
            s1 += f * a_src[h * C + c0 + k];
            s2 += f * a_dst[h * C + c0 + k];
        }
    }
    als[i] = s1;
    ald[i] = s2;
}

// ---------------- H=8 aggregate: wave-per-node, fused edge weights ----------------
// Pass A: stage scol, gather als rows from L2 (1.6 MB resident), compute
// w = exp(lrelu(als+ald)) in-kernel, cache in se[edge][head], per-(slot,head)
// partial sums -> shfl reduce across slots -> __shfl hands each lane its head.

__global__ __launch_bounds__(256)
void gat_agg_w8(const unsigned short* __restrict__ hfeat,
                const float* __restrict__ als, const float* __restrict__ ald,
                const int* __restrict__ rowptr,           // shifted: rowptr[n] = END
                const int* __restrict__ col,
                const float* __restrict__ bias,
                unsigned short* __restrict__ outH, unsigned short* __restrict__ outL,
                int N) {
    constexpr int CAP = 128;
    const int wid = threadIdx.x >> 6;
    const int lane = threadIdx.x & 63;
    const int n = blockIdx.x * 4 + wid;
    __shared__ float se_all[4][CAP * 8];
    __shared__ int scol_all[4][CAP];
    if (n >= N) return;
    float* se = se_all[wid];
    int* scol = scol_all[wid];

    const int r0 = (n == 0) ? 0 : rowptr[n - 1];
    const int deg = rowptr[n] - r0;
    const int dcap = min(deg, CAP);

    // stage col -> LDS (coalesced; same wave reads below, no barrier needed)
    for (int j = lane; j < dcap; j += 64) scol[j] = col[r0 + j];

    // ---- pass A: fused weights; slot = lane>>3 (edge), h = lane&7 (head) ----
    const int slot = lane >> 3, h = lane & 7;
    const float aldh = ald[(size_t)n * 8 + h];
    float psum = 0.f;
    for (int j = 0; j < deg; j += 8) {
        int e = j + slot;
        if (e < deg) {
            int s = (e < dcap) ? scol[e] : col[r0 + e];
            float ev = als[(size_t)s * 8 + h] + aldh;
            ev = LRELU(ev);
            float w = __expf(ev);
            psum += w;
            if (e < CAP) se[e * 8 + h] = w;
        }
    }
#pragma unroll
    for (int m = 8; m < 64; m <<= 1) psum += __shfl_xor(psum, m);
    const int q = lane >> 3;                 // this lane's head in pass B
    const float sinv = 1.0f / __shfl(psum, q);
    const float aldq = ald[(size_t)n * 8 + q];

    // ---- pass B: 4-deep gather (R7 form) ----
    const int cb = lane * 4;
    float a0 = 0.f, a1 = 0.f, a2 = 0.f, a3 = 0.f;
    int j = 0;
    for (; j + 3 < dcap; j += 4) {
        int s0 = __builtin_amdgcn_readfirstlane(scol[j]);
        int s1 = __builtin_amdgcn_readfirstlane(scol[j + 1]);
        int s2 = __builtin_amdgcn_readfirstlane(scol[j + 2]);
        int s3 = __builtin_amdgcn_readfirstlane(scol[j + 3]);
        ushort4v v0 = *(const ushort4v*)(hfeat + (size_t)s0 * 256 + cb);
        ushort4v v1 = *(const ushort4v*)(hfeat + (size_t)s1 * 256 + cb);
        ushort4v v2 = *(const ushort4v*)(hfeat + (size_t)s2 * 256 + cb);
        ushort4v v3 = *(const ushort4v*)(hfeat + (size_t)s3 * 256 + cb);
        float w0 = se[j * 8 + q];
        float w1 = se[j * 8 + 8 + q];
        float w2 = se[j * 8 + 16 + q];
        float w3 = se[j * 8 + 24 + q];
        a0 += bf2f(v0[0]) * w0; a1 += bf2f(v0[1]) * w0; a2 += bf2f(v0[2]) * w0; a3 += bf2f(v0[3]) * w0;
        a0 += bf2f(v1[0]) * w1; a1 += bf2f(v1[1]) * w1; a2 += bf2f(v1[2]) * w1; a3 += bf2f(v1[3]) * w1;
        a0 += bf2f(v2[0]) * w2; a1 += bf2f(v2[1]) * w2; a2 += bf2f(v2[2]) * w2; a3 += bf2f(v2[3]) * w2;
        a0 += bf2f(v3[0]) * w3; a1 += bf2f(v3[1]) * w3; a2 += bf2f(v3[2]) * w3; a3 += bf2f(v3[3]) * w3;
    }
    for (; j < dcap; j++) {
        int s0 = __builtin_amdgcn_readfirstlane(scol[j]);
        ushort4v v0 = *(const ushort4v*)(hfeat + (size_t)s0 * 256 + cb);
        float w0 = se[j * 8 + q];
        a0 += bf2f(v0[0]) * w0; a1 += bf2f(v0[1]) * w0; a2 += bf2f(v0[2]) * w0; a3 += bf2f(v0[3]) * w0;
    }
    for (; j < deg; j++) {                   // deg > CAP fallback (essentially never)
        int s0 = col[r0 + j];
        float ev = als[(size_t)s0 * 8 + q] + aldq;
        ev = LRELU(ev);
        float w0 = __expf(ev);
        ushort4v v0 = *(const ushort4v*)(hfeat + (size_t)s0 * 256 + cb);
        a0 += bf2f(v0[0]) * w0; a1 += bf2f(v0[1]) * w0; a2 += bf2f(v0[2]) * w0; a3 += bf2f(v0[3]) * w0;
    }

    // ---- epilogue: normalize + bias + relu + hi/lo split store ----
    float4 b4 = *(const float4*)&bias[cb];
    float o0 = fmaxf(a0 * sinv + b4.x, 0.f);
    float o1 = fmaxf(a1 * sinv + b4.y, 0.f);
    float o2 = fmaxf(a2 * sinv + b4.z, 0.f);
    float o3 = fmaxf(a3 * sinv + b4.w, 0.f);
    unsigned short h0 = f2bf(o0), h1 = f2bf(o1), h2 = f2bf(o2), h3 = f2bf(o3);
    const size_t ob = (size_t)n * 256 + cb;
    *(ushort4v*)&outH[ob] = (ushort4v){h0, h1, h2, h3};
    *(ushort4v*)&outL[ob] = (ushort4v){f2bf(o0 - bf2f(h0)), f2bf(o1 - bf2f(h1)),
                                       f2bf(o2 - bf2f(h2)), f2bf(o3 - bf2f(h3))};
}

// ---------------- H=1 aggregate: wave-per-node, fused weights ----------------

__global__ __launch_bounds__(256)
void gat_agg_h1w(const unsigned short* __restrict__ hfeat,
                 const float* __restrict__ als, const float* __restrict__ ald,
                 const int* __restrict__ rowptr, const int* __restrict__ col,
                 const float* __restrict__ bias, float* __restrict__ out, int N) {
    constexpr int CAP = 256;
    const int wid = threadIdx.x >> 6;
    const int lane = threadIdx.x & 63;
    const int n = blockIdx.x * 4 + wid;
    __shared__ float sw_all[4][CAP];
    __shared__ int scol_all[4][CAP];
    if (n >= N) return;
    float* sw = sw_all[wid];
    int* scol = scol_all[wid];

    const int r0 = (n == 0) ? 0 : rowptr[n - 1];
    const int deg = rowptr[n] - r0;
    const int dcap = min(deg, CAP);
    const float aldn = ald[n];

    float lsum = 0.f;
    for (int idx = lane; idx < deg; idx += 64) {
        int s = col[r0 + idx];
        float ev = als[s] + aldn;
        ev = LRELU(ev);
        float w = __expf(ev);
        if (idx < CAP) { sw[idx] = w; scol[idx] = s; }
        lsum += w;
    }
#pragma unroll
    for (int m = 1; m < 64; m <<= 1) lsum += __shfl_xor(lsum, m);
    const float sinv = 1.0f / lsum;

    const int slot = lane >> 3, ch = lane & 7;
    float a0 = 0.f, a1 = 0.f, a2 = 0.f, a3 = 0.f;
    for (int j = 0; j < dcap; j += 8) {
        int e = j + slot;
        int ec = min(e, dcap - 1);
        int s = scol[ec];
        float w = (e < dcap) ? sw[ec] : 0.f;
        ushort4v v = *(const ushort4v*)(hfeat + (size_t)s * 32 + ch * 4);
        a0 += bf2f(v[0]) * w; a1 += bf2f(v[1]) * w;
        a2 += bf2f(v[2]) * w; a3 += bf2f(v[3]) * w;
    }
    for (int j = CAP; j < deg; j += 8) {     // deg > CAP fallback
        int e = j + slot;
        int ec = min(e, deg - 1);
        int s = col[r0 + ec];
        float w = 0.f;
        if (e < deg) {
            float ev = als[s] + aldn;
            ev = LRELU(ev);
            w = __expf(ev);
        }
        ushort4v v = *(const ushort4v*)(hfeat + (size_t)s * 32 + ch * 4);
        a0 += bf2f(v[0]) * w; a1 += bf2f(v[1]) * w;
        a2 += bf2f(v[2]) * w; a3 += bf2f(v[3]) * w;
    }
#pragma unroll
    for (int m = 8; m < 64; m <<= 1) {
        a0 += __shfl_xor(a0, m);
        a1 += __shfl_xor(a1, m);
        a2 += __shfl_xor(a2, m);
        a3 += __shfl_xor(a3, m);
    }
    if (slot == 0) {
        float4 b4 = *(const float4*)&bias[ch * 4];
        float4 o;
        o.x = a0 * sinv + b4.x;
        o.y = a1 * sinv + b4.y;
        o.z = a2 * sinv + b4.z;
        o.w = a3 * sinv + b4.w;
        *(float4*)&out[(size_t)n * 32 + ch * 4] = o;
    }
}

// ---------------- fused pool + head (sorted batch, no atomics) ----------------

__global__ __launch_bounds__(256)
void pool_final_kernel(const float* __restrict__ h, const int* __restrict__ gstart,
                       const float* __restrict__ lin_w, const float* __restrict__ lin_b,
                       float* __restrict__ out) {
    const int g = blockIdx.x;
    const int tid = threadIdx.x;
    const int n0 = gstart[g], n1 = gstart[g + 1];
    const int r = tid >> 5, c = tid & 31;
    __shared__ float pp[4][32];
    __shared__ float pm[32];
    float acc = 0.f;
    for (int n = n0 + r; n < n1; n += 8) acc += h[(size_t)n * 32 + c];
    acc += __shfl_xor(acc, 32);
    if ((tid & 63) < 32) pp[tid >> 6][c] = acc;
    __syncthreads();
    if (tid < 32) {
        float s = pp[0][tid] + pp[1][tid] + pp[2][tid] + pp[3][tid];
        pm[tid] = s / fmaxf((float)(n1 - n0), 1.f);
    }
    __syncthreads();
    if (tid < 64) {
        float a = lin_b[tid];
#pragma unroll 8
        for (int cc = 0; cc < 32; cc++) a += pm[cc] * lin_w[cc * 64 + tid];
        out[(size_t)g * 64 + tid] = a;
    }
}

// ---------------- launch ----------------

extern "C" void kernel_launch(void* const* d_in, const int* in_sizes, int n_in,
                              void* d_out, int out_size, void* d_ws, size_t ws_size,
                              hipStream_t stream) {
    const float* x     = (const float*)d_in[0];
    const int*   ei    = (const int*)d_in[1];
    const int*   batch = (const int*)d_in[2];
    const float* W0    = (const float*)d_in[3];
    const float* a_s0  = (const float*)d_in[4];
    const float* a_d0  = (const float*)d_in[5];
    const float* b0    = (const float*)d_in[6];
    const float* W1    = (const float*)d_in[7];
    const float* a_s1  = (const float*)d_in[8];
    const float* a_d1  = (const float*)d_in[9];
    const float* b1    = (const float*)d_in[10];
    const float* W2    = (const float*)d_in[11];
    const float* a_s2  = (const float*)d_in[12];
    const float* a_d2  = (const float*)d_in[13];
    const float* b2    = (const float*)d_in[14];
    const float* lin_w = (const float*)d_in[15];
    const float* lin_b = (const float*)d_in[16];

    const int N = in_sizes[0] / 128;   // 50000
    const int E = in_sizes[1] / 2;     // 1600000
    const int G = 256;
    const int Etot = E + N;
    const int* src = ei;
    const int* dst = ei + E;

    char* w = (char*)d_ws;
    size_t off = 0;
    auto alloc = [&](size_t bytes) -> void* {
        void* p = (void*)(w + off);
        off += (bytes + 255) & ~(size_t)255;
        return p;
    };
    int* deg    = (int*)alloc((size_t)N * 4);
    int* rowptr = (int*)alloc((size_t)(N + 1) * 4);
    int* colA   = (int*)alloc((size_t)Etot * 4);
    int* gstart = (int*)alloc((size_t)(G + 1) * 4);
    float* als  = (float*)alloc((size_t)N * 8 * 4);
    float* ald  = (float*)alloc((size_t)N * 8 * 4);
    unsigned short* hb  = (unsigned short*)alloc((size_t)N * 256 * 2);
    unsigned short* g0h = (unsigned short*)alloc((size_t)N * 256 * 2);
    unsigned short* g0l = (unsigned short*)alloc((size_t)N * 256 * 2);
    float* out2 = (float*)alloc((size_t)N * 32 * 4);
    unsigned short* w0h = (unsigned short*)alloc((size_t)128 * 256 * 2);
    unsigned short* w0l = (unsigned short*)alloc((size_t)128 * 256 * 2);
    unsigned short* w1h = (unsigned short*)alloc((size_t)256 * 256 * 2);
    unsigned short* w1l = (unsigned short*)alloc((size_t)256 * 256 * 2);
    unsigned short* w2h = (unsigned short*)alloc((size_t)256 * 32 * 2);
    unsigned short* w2l = (unsigned short*)alloc((size_t)256 * 32 * 2);
    unsigned short* xh = g0h;                       // aliased: dead before agg0 writes g0h
    unsigned short* xl = g0h + (size_t)N * 128;

    hipMemsetAsync(deg, 0, (size_t)N * 4, stream);

    // CSR (shifted convention after scatter) + graph offsets
    deg_kernel<<<(Etot + 255) / 256, 256, 0, stream>>>(dst, deg, E, N);
    scan_kernel<<<1, 1024, 0, stream>>>(deg, rowptr, N);
    for (int p = 0; p < 2; p++) {
        int lo = (int)((size_t)N * p / 2);
        int hi = (int)((size_t)N * (p + 1) / 2);
        scatter_col_binned<<<(Etot + 255) / 256, 256, 0, stream>>>(src, dst, rowptr, colA, E, N, lo, hi);
    }
    gstart_kernel<<<2, 256, 0, stream>>>(batch, gstart, N, G);

    split_plain_kernel<<<(N * 128 + 255) / 256, 256, 0, stream>>>(x, xh, xl, N * 128);
    splitT_kernel<<<(128 * 256 + 255) / 256, 256, 0, stream>>>(W0, w0h, w0l, 128, 256);
    splitT_kernel<<<(256 * 256 + 255) / 256, 256, 0, stream>>>(W1, w1h, w1l, 256, 256);
    splitT_kernel<<<(256 * 32 + 255) / 256, 256, 0, stream>>>(W2, w2h, w2l, 256, 32);

    const int MB = (N + 127) / 128;

    // layer 0: K=128
    gemm_mfma_v2<128, 128, 64, 64><<<dim3(2, MB), 256, 0, stream>>>(xh, xl, w0h, w0l, hb, N, 256, 128);
    al_bf16<8, 32><<<(N * 8 + 255) / 256, 256, 0, stream>>>(hb, a_s0, a_d0, als, ald, N);
    gat_agg_w8<<<(N + 3) / 4, 256, 0, stream>>>(hb, als, ald, rowptr, colA, b0, g0h, g0l, N);

    // layer 1: K=256
    gemm_mfma_v2<128, 128, 64, 64><<<dim3(2, MB), 256, 0, stream>>>(g0h, g0l, w1h, w1l, hb, N, 256, 256);
    al_bf16<8, 32><<<(N * 8 + 255) / 256, 256, 0, stream>>>(hb, a_s1, a_d1, als, ald, N);
    gat_agg_w8<<<(N + 3) / 4, 256, 0, stream>>>(hb, als, ald, rowptr, colA, b1, g0h, g0l, N);

    // layer 2: heads=1, C=32, K=256
    gemm_mfma_v2<128, 32, 32, 32><<<dim3(1, MB), 256, 0, stream>>>(g0h, g0l, w2h, w2l, hb, N, 32, 256);
    al_bf16<1, 32><<<(N + 255) / 256, 256, 0, stream>>>(hb, a_s2, a_d2, als, ald, N);
    gat_agg_h1w<<<(N + 3) / 4, 256, 0, stream>>>(hb, als, ald, rowptr, colA, b2, out2, N);

    // fused pool + head
    pool_final_kernel<<<G, 256, 0, stream>>>(out2, gstart, lin_w, lin_b, (float*)d_out);
}

// Round 11
// 639.938 us; speedup vs baseline: 1.0841x; 1.0454x over previous
//
#include <hip/hip_runtime.h>
#include <hip/hip_bf16.h>

// ---------------------------------------------------------------------------
// GAT (3 layers) + global mean pool + linear head.
// R11: GEMMs dropped from 3-term split-bf16 to plain bf16 (1 MFMA term,
// BK=64, half the staging/LDS/barriers) — spends ~2x of the 4.6x accuracy
// headroom. Agg epilogue loses the lo-plane write (WRITE halved).
// ---------------------------------------------------------------------------

#define LRELU(x) ((x) >= 0.f ? (x) : 0.2f * (x))

typedef unsigned short ushort8 __attribute__((ext_vector_type(8)));
typedef unsigned short ushort4v __attribute__((ext_vector_type(4)));
typedef __attribute__((ext_vector_type(8))) short bf16x8;
typedef __attribute__((ext_vector_type(4))) float f32x4;

__device__ __forceinline__ float bf2f(unsigned short u) {
    return __uint_as_float(((unsigned)u) << 16);
}
__device__ __forceinline__ unsigned short f2bf(float f) {
    __hip_bfloat16 b = __float2bfloat16(f);
    return *reinterpret_cast<unsigned short*>(&b);
}
__device__ __forceinline__ void gl_lds16(const unsigned short* g, unsigned short* l) {
    __builtin_amdgcn_global_load_lds((const __attribute__((address_space(1))) void*)g,
                                     (__attribute__((address_space(3))) void*)l, 16, 0, 0);
}

// ---------------- CSR build ----------------

__global__ void deg_kernel(const int* __restrict__ dst, int* __restrict__ deg,
                           int E, int N) {
    int i = blockIdx.x * blockDim.x + threadIdx.x;
    if (i < E) atomicAdd(&deg[dst[i]], 1);
    else if (i < E + N) atomicAdd(&deg[i - E], 1);   // self loop
}

__global__ void scan_kernel(const int* __restrict__ deg, int* __restrict__ rowptr,
                            int n) {
    __shared__ int partial[1024];
    const int tid = threadIdx.x;
    const int chunk = (n + 1023) / 1024;
    const int start = min(tid * chunk, n);
    const int end = min(start + chunk, n);
    int s = 0;
    for (int i = start; i < end; i++) s += deg[i];
    partial[tid] = s;
    __syncthreads();
    for (int o = 1; o < 1024; o <<= 1) {
        int v = (tid >= o) ? partial[tid - o] : 0;
        __syncthreads();
        partial[tid] += v;
        __syncthreads();
    }
    int run = (tid == 0) ? 0 : partial[tid - 1];
    for (int i = start; i < end; i++) { rowptr[i] = run; run += deg[i]; }
    if (tid == 0) rowptr[n] = partial[1023];
}

// Binned scatter on rowptr itself: after both passes rowptr[n] = END of
// segment n (start = rowptr[n-1], 0 for n=0) — shifted convention.
__global__ void scatter_col_binned(const int* __restrict__ src, const int* __restrict__ dst,
                                   int* __restrict__ rowptr, int* __restrict__ col,
                                   int E, int N, int lo, int hi) {
    int i = blockIdx.x * blockDim.x + threadIdx.x;
    if (i < E) {
        int d = dst[i];
        if (d < lo || d >= hi) return;
        int pos = atomicAdd(&rowptr[d], 1);
        col[pos] = src[i];
    } else if (i < E + N) {
        int d = i - E;
        if (d < lo || d >= hi) return;
        int pos = atomicAdd(&rowptr[d], 1);
        col[pos] = d;
    }
}

__global__ void gstart_kernel(const int* __restrict__ batch, int* __restrict__ gstart,
                              int N, int G) {
    int g = blockIdx.x * blockDim.x + threadIdx.x;
    if (g > G) return;
    int lo = 0, hi = N;
    while (lo < hi) { int mid = (lo + hi) >> 1; if (batch[mid] < g) lo = mid + 1; else hi = mid; }
    gstart[g] = lo;
}

// ---------------- f32 -> bf16 helpers ----------------

__global__ void round_bf16_kernel(const float* __restrict__ X, unsigned short* __restrict__ o,
                                  int n) {
    int i = blockIdx.x * blockDim.x + threadIdx.x;
    if (i >= n) return;
    o[i] = f2bf(X[i]);
}

// W[K][N] -> Wt[N][K] bf16
__global__ void transT_bf16_kernel(const float* __restrict__ W, unsigned short* __restrict__ t,
                                   int K, int N) {
    int i = blockIdx.x * blockDim.x + threadIdx.x;
    if (i >= N * K) return;
    int n = i / K, k = i - n * K;
    t[i] = f2bf(W[(size_t)k * N + n]);
}

// ---------------- plain-bf16 MFMA GEMM, BK=64, global_load_lds staging ----------------
// C[M,N](bf16) = A[M,K](bf16) @ B[K,N], B given transposed [N][K] bf16.

template <int BM, int BN, int WM, int WN>
__global__ __launch_bounds__(256)
void gemm_bf16_1t(const unsigned short* __restrict__ A, const unsigned short* __restrict__ Bt,
                  unsigned short* __restrict__ Cc, int M, int N, int K) {
    constexpr int BK = 64;
    constexpr int MT = WM / 16, NT = WN / 16;
    constexpr int NWX = BN / WN;
    __shared__ __attribute__((aligned(16))) unsigned short Ab[BM][BK];
    __shared__ __attribute__((aligned(16))) unsigned short Bb[BN][BK];
    const int tid = threadIdx.x;
    const int lane = tid & 63;
    const int wave = tid >> 6;
    const int wx = wave % NWX, wy = wave / NWX;
    const int by = blockIdx.y * BM;
    const int bx = blockIdx.x * BN;
    const int r16 = lane & 15, kg = lane >> 4;
    const int srow = lane >> 3, sslot = lane & 7;   // staging: 8 rows x 8 slots per call

    f32x4 acc[MT][NT];
#pragma unroll
    for (int i = 0; i < MT; i++)
#pragma unroll
        for (int j = 0; j < NT; j++) acc[i][j] = (f32x4){0.f, 0.f, 0.f, 0.f};

    for (int k0 = 0; k0 < K; k0 += BK) {
        // A tile: BM x 64 bf16; one gl_lds16 call fills 8 rows (64 lanes x 16B).
        // OOB rows clamped: garbage only lands in C rows >= M, never stored.
        for (int t = wave; t < BM / 8; t += 4) {
            int gm = by + t * 8 + srow;
            if (gm >= M) gm = M - 1;
            gl_lds16(A + (size_t)gm * K + k0 + sslot * 8, &Ab[t * 8][0]);
        }
        for (int t = wave; t < BN / 8; t += 4) {
            int gn = bx + t * 8 + srow;
            gl_lds16(Bt + (size_t)gn * K + k0 + sslot * 8, &Bb[t * 8][0]);
        }
        __syncthreads();
#pragma unroll
        for (int ks = 0; ks < 2; ks++) {
            bf16x8 bh[NT];
#pragma unroll
            for (int j = 0; j < NT; j++)
                bh[j] = *(const bf16x8*)&Bb[wx * WN + j * 16 + r16][ks * 32 + kg * 8];
#pragma unroll
            for (int i = 0; i < MT; i++) {
                bf16x8 ah = *(const bf16x8*)&Ab[wy * WM + i * 16 + r16][ks * 32 + kg * 8];
#pragma unroll
                for (int j = 0; j < NT; j++)
                    acc[i][j] = __builtin_amdgcn_mfma_f32_16x16x32_bf16(ah, bh[j], acc[i][j], 0, 0, 0);
            }
        }
        __syncthreads();
    }
    // epilogue: D row = (lane>>4)*4 + reg, col = lane&15 (m89-verified, R5-R10 passed)
#pragma unroll
    for (int i = 0; i < MT; i++) {
#pragma unroll
        for (int r = 0; r < 4; r++) {
            int gm = by + wy * WM + i * 16 + kg * 4 + r;
            if (gm >= M) continue;
#pragma unroll
            for (int j = 0; j < NT; j++) {
                int gn = bx + wx * WN + j * 16 + r16;
                Cc[(size_t)gm * N + gn] = f2bf(acc[i][j][r]);
            }
        }
    }
}

// ---------------- per-node attention logits (bf16 h, 16B loads) ----------------

template <int H, int C>
__global__ void al_bf16(const unsigned short* __restrict__ hfeat, const float* __restrict__ a_src,
                        const float* __restrict__ a_dst, float* __restrict__ als,
                        float* __restrict__ ald, int N) {
    int i = blockIdx.x * blockDim.x + threadIdx.x;
    if (i >= N * H) return;
    int n = i / H, h = i % H;
    const unsigned short* hp = hfeat + (size_t)n * H * C + h * C;
    float s1 = 0.f, s2 = 0.f;
    for (int c0 = 0; c0 < C; c0 += 8) {
        ushort8 v = *(const ushort8*)(hp + c0);
#pragma unroll
        for (int k = 0; k < 8; k++) {
            float f = bf2f(v[k]);
            s1 += f * a_src[h * C + c0 + k];
            s2 += f * a_dst[h * C + c0 + k];
        }
    }
    als[i] = s1;
    ald[i] = s2;
}

// ---------------- H=8 aggregate: wave-per-node, fused edge weights ----------------

__global__ __launch_bounds__(256)
void gat_agg_w8(const unsigned short* __restrict__ hfeat,
                const float* __restrict__ als, const float* __restrict__ ald,
                const int* __restrict__ rowptr,           // shifted: rowptr[n] = END
                const int* __restrict__ col,
                const float* __restrict__ bias,
                unsigned short* __restrict__ outH,
                int N) {
    constexpr int CAP = 128;
    const int wid = threadIdx.x >> 6;
    const int lane = threadIdx.x & 63;
    const int n = blockIdx.x * 4 + wid;
    __shared__ float se_all[4][CAP * 8];
    __shared__ int scol_all[4][CAP];
    if (n >= N) return;
    float* se = se_all[wid];
    int* scol = scol_all[wid];

    const int r0 = (n == 0) ? 0 : rowptr[n - 1];
    const int deg = rowptr[n] - r0;
    const int dcap = min(deg, CAP);

    // stage col -> LDS (coalesced; same wave reads below, no barrier needed)
    for (int j = lane; j < dcap; j += 64) scol[j] = col[r0 + j];

    // ---- pass A: fused weights; slot = lane>>3 (edge), h = lane&7 (head) ----
    const int slot = lane >> 3, h = lane & 7;
    const float aldh = ald[(size_t)n * 8 + h];
    float psum = 0.f;
    for (int j = 0; j < deg; j += 8) {
        int e = j + slot;
        if (e < deg) {
            int s = (e < dcap) ? scol[e] : col[r0 + e];
            float ev = als[(size_t)s * 8 + h] + aldh;
            ev = LRELU(ev);
            float w = __expf(ev);
            psum += w;
            if (e < CAP) se[e * 8 + h] = w;
        }
    }
#pragma unroll
    for (int m = 8; m < 64; m <<= 1) psum += __shfl_xor(psum, m);
    const int q = lane >> 3;                 // this lane's head in pass B
    const float sinv = 1.0f / __shfl(psum, q);
    const float aldq = ald[(size_t)n * 8 + q];

    // ---- pass B: 4-deep gather ----
    const int cb = lane * 4;
    float a0 = 0.f, a1 = 0.f, a2 = 0.f, a3 = 0.f;
    int j = 0;
    for (; j + 3 < dcap; j += 4) {
        int s0 = __builtin_amdgcn_readfirstlane(scol[j]);
        int s1 = __builtin_amdgcn_readfirstlane(scol[j + 1]);
        int s2 = __builtin_amdgcn_readfirstlane(scol[j + 2]);
        int s3 = __builtin_amdgcn_readfirstlane(scol[j + 3]);
        ushort4v v0 = *(const ushort4v*)(hfeat + (size_t)s0 * 256 + cb);
        ushort4v v1 = *(const ushort4v*)(hfeat + (size_t)s1 * 256 + cb);
        ushort4v v2 = *(const ushort4v*)(hfeat + (size_t)s2 * 256 + cb);
        ushort4v v3 = *(const ushort4v*)(hfeat + (size_t)s3 * 256 + cb);
        float w0 = se[j * 8 + q];
        float w1 = se[j * 8 + 8 + q];
        float w2 = se[j * 8 + 16 + q];
        float w3 = se[j * 8 + 24 + q];
        a0 += bf2f(v0[0]) * w0; a1 += bf2f(v0[1]) * w0; a2 += bf2f(v0[2]) * w0; a3 += bf2f(v0[3]) * w0;
        a0 += bf2f(v1[0]) * w1; a1 += bf2f(v1[1]) * w1; a2 += bf2f(v1[2]) * w1; a3 += bf2f(v1[3]) * w1;
        a0 += bf2f(v2[0]) * w2; a1 += bf2f(v2[1]) * w2; a2 += bf2f(v2[2]) * w2; a3 += bf2f(v2[3]) * w2;
        a0 += bf2f(v3[0]) * w3; a1 += bf2f(v3[1]) * w3; a2 += bf2f(v3[2]) * w3; a3 += bf2f(v3[3]) * w3;
    }
    for (; j < dcap; j++) {
        int s0 = __builtin_amdgcn_readfirstlane(scol[j]);
        ushort4v v0 = *(const ushort4v*)(hfeat + (size_t)s0 * 256 + cb);
        float w0 = se[j * 8 + q];
        a0 += bf2f(v0[0]) * w0; a1 += bf2f(v0[1]) * w0; a2 += bf2f(v0[2]) * w0; a3 += bf2f(v0[3]) * w0;
    }
    for (; j < deg; j++) {                   // deg > CAP fallback (essentially never)
        int s0 = col[r0 + j];
        float ev = als[(size_t)s0 * 8 + q] + aldq;
        ev = LRELU(ev);
        float w0 = __expf(ev);
        ushort4v v0 = *(const ushort4v*)(hfeat + (size_t)s0 * 256 + cb);
        a0 += bf2f(v0[0]) * w0; a1 += bf2f(v0[1]) * w0; a2 += bf2f(v0[2]) * w0; a3 += bf2f(v0[3]) * w0;
    }

    // ---- epilogue: normalize + bias + relu + bf16 store ----
    float4 b4 = *(const float4*)&bias[cb];
    float o0 = fmaxf(a0 * sinv + b4.x, 0.f);
    float o1 = fmaxf(a1 * sinv + b4.y, 0.f);
    float o2 = fmaxf(a2 * sinv + b4.z, 0.f);
    float o3 = fmaxf(a3 * sinv + b4.w, 0.f);
    const size_t ob = (size_t)n * 256 + cb;
    *(ushort4v*)&outH[ob] = (ushort4v){f2bf(o0), f2bf(o1), f2bf(o2), f2bf(o3)};
}

// ---------------- H=1 aggregate: wave-per-node, fused weights ----------------

__global__ __launch_bounds__(256)
void gat_agg_h1w(const unsigned short* __restrict__ hfeat,
                 const float* __restrict__ als, const float* __restrict__ ald,
                 const int* __restrict__ rowptr, const int* __restrict__ col,
                 const float* __restrict__ bias, float* __restrict__ out, int N) {
    constexpr int CAP = 256;
    const int wid = threadIdx.x >> 6;
    const int lane = threadIdx.x & 63;
    const int n = blockIdx.x * 4 + wid;
    __shared__ float sw_all[4][CAP];
    __shared__ int scol_all[4][CAP];
    if (n >= N) return;
    float* sw = sw_all[wid];
    int* scol = scol_all[wid];

    const int r0 = (n == 0) ? 0 : rowptr[n - 1];
    const int deg = rowptr[n] - r0;
    const int dcap = min(deg, CAP);
    const float aldn = ald[n];

    float lsum = 0.f;
    for (int idx = lane; idx < deg; idx += 64) {
        int s = col[r0 + idx];
        float ev = als[s] + aldn;
        ev = LRELU(ev);
        float w = __expf(ev);
        if (idx < CAP) { sw[idx] = w; scol[idx] = s; }
        lsum += w;
    }
#pragma unroll
    for (int m = 1; m < 64; m <<= 1) lsum += __shfl_xor(lsum, m);
    const float sinv = 1.0f / lsum;

    const int slot = lane >> 3, ch = lane & 7;
    float a0 = 0.f, a1 = 0.f, a2 = 0.f, a3 = 0.f;
    for (int j = 0; j < dcap; j += 8) {
        int e = j + slot;
        int ec = min(e, dcap - 1);
        int s = scol[ec];
        float w = (e < dcap) ? sw[ec] : 0.f;
        ushort4v v = *(const ushort4v*)(hfeat + (size_t)s * 32 + ch * 4);
        a0 += bf2f(v[0]) * w; a1 += bf2f(v[1]) * w;
        a2 += bf2f(v[2]) * w; a3 += bf2f(v[3]) * w;
    }
    for (int j = CAP; j < deg; j += 8) {     // deg > CAP fallback
        int e = j + slot;
        int ec = min(e, deg - 1);
        int s = col[r0 + ec];
        float w = 0.f;
        if (e < deg) {
            float ev = als[s] + aldn;
            ev = LRELU(ev);
            w = __expf(ev);
        }
        ushort4v v = *(const ushort4v*)(hfeat + (size_t)s * 32 + ch * 4);
        a0 += bf2f(v[0]) * w; a1 += bf2f(v[1]) * w;
        a2 += bf2f(v[2]) * w; a3 += bf2f(v[3]) * w;
    }
#pragma unroll
    for (int m = 8; m < 64; m <<= 1) {
        a0 += __shfl_xor(a0, m);
        a1 += __shfl_xor(a1, m);
        a2 += __shfl_xor(a2, m);
        a3 += __shfl_xor(a3, m);
    }
    if (slot == 0) {
        float4 b4 = *(const float4*)&bias[ch * 4];
        float4 o;
        o.x = a0 * sinv + b4.x;
        o.y = a1 * sinv + b4.y;
        o.z = a2 * sinv + b4.z;
        o.w = a3 * sinv + b4.w;
        *(float4*)&out[(size_t)n * 32 + ch * 4] = o;
    }
}

// ---------------- fused pool + head (sorted batch, no atomics) ----------------

__global__ __launch_bounds__(256)
void pool_final_kernel(const float* __restrict__ h, const int* __restrict__ gstart,
                       const float* __restrict__ lin_w, const float* __restrict__ lin_b,
                       float* __restrict__ out) {
    const int g = blockIdx.x;
    const int tid = threadIdx.x;
    const int n0 = gstart[g], n1 = gstart[g + 1];
    const int r = tid >> 5, c = tid & 31;
    __shared__ float pp[4][32];
    __shared__ float pm[32];
    float acc = 0.f;
    for (int n = n0 + r; n < n1; n += 8) acc += h[(size_t)n * 32 + c];
    acc += __shfl_xor(acc, 32);
    if ((tid & 63) < 32) pp[tid >> 6][c] = acc;
    __syncthreads();
    if (tid < 32) {
        float s = pp[0][tid] + pp[1][tid] + pp[2][tid] + pp[3][tid];
        pm[tid] = s / fmaxf((float)(n1 - n0), 1.f);
    }
    __syncthreads();
    if (tid < 64) {
        float a = lin_b[tid];
#pragma unroll 8
        for (int cc = 0; cc < 32; cc++) a += pm[cc] * lin_w[cc * 64 + tid];
        out[(size_t)g * 64 + tid] = a;
    }
}

// ---------------- launch ----------------

extern "C" void kernel_launch(void* const* d_in, const int* in_sizes, int n_in,
                              void* d_out, int out_size, void* d_ws, size_t ws_size,
                              hipStream_t stream) {
    const float* x     = (const float*)d_in[0];
    const int*   ei    = (const int*)d_in[1];
    const int*   batch = (const int*)d_in[2];
    const float* W0    = (const float*)d_in[3];
    const float* a_s0  = (const float*)d_in[4];
    const float* a_d0  = (const float*)d_in[5];
    const float* b0    = (const float*)d_in[6];
    const float* W1    = (const float*)d_in[7];
    const float* a_s1  = (const float*)d_in[8];
    const float* a_d1  = (const float*)d_in[9];
    const float* b1    = (const float*)d_in[10];
    const float* W2    = (const float*)d_in[11];
    const float* a_s2  = (const float*)d_in[12];
    const float* a_d2  = (const float*)d_in[13];
    const float* b2    = (const float*)d_in[14];
    const float* lin_w = (const float*)d_in[15];
    const float* lin_b = (const float*)d_in[16];

    const int N = in_sizes[0] / 128;   // 50000
    const int E = in_sizes[1] / 2;     // 1600000
    const int G = 256;
    const int Etot = E + N;
    const int* src = ei;
    const int* dst = ei + E;

    char* w = (char*)d_ws;
    size_t off = 0;
    auto alloc = [&](size_t bytes) -> void* {
        void* p = (void*)(w + off);
        off += (bytes + 255) & ~(size_t)255;
        return p;
    };
    int* deg    = (int*)alloc((size_t)N * 4);
    int* rowptr = (int*)alloc((size_t)(N + 1) * 4);
    int* colA   = (int*)alloc((size_t)Etot * 4);
    int* gstart = (int*)alloc((size_t)(G + 1) * 4);
    float* als  = (float*)alloc((size_t)N * 8 * 4);
    float* ald  = (float*)alloc((size_t)N * 8 * 4);
    unsigned short* hb  = (unsigned short*)alloc((size_t)N * 256 * 2);   // GEMM output
    unsigned short* g0  = (unsigned short*)alloc((size_t)N * 256 * 2);   // agg output
    float* out2 = (float*)alloc((size_t)N * 32 * 4);
    unsigned short* w0t = (unsigned short*)alloc((size_t)256 * 128 * 2); // W0^T bf16
    unsigned short* w1t = (unsigned short*)alloc((size_t)256 * 256 * 2);
    unsigned short* w2t = (unsigned short*)alloc((size_t)32 * 256 * 2);
    unsigned short* xb = g0;                        // x bf16, aliased (dead before agg0 writes g0)

    hipMemsetAsync(deg, 0, (size_t)N * 4, stream);

    // CSR (shifted convention after scatter) + graph offsets
    deg_kernel<<<(Etot + 255) / 256, 256, 0, stream>>>(dst, deg, E, N);
    scan_kernel<<<1, 1024, 0, stream>>>(deg, rowptr, N);
    for (int p = 0; p < 2; p++) {
        int lo = (int)((size_t)N * p / 2);
        int hi = (int)((size_t)N * (p + 1) / 2);
        scatter_col_binned<<<(Etot + 255) / 256, 256, 0, stream>>>(src, dst, rowptr, colA, E, N, lo, hi);
    }
    gstart_kernel<<<2, 256, 0, stream>>>(batch, gstart, N, G);

    round_bf16_kernel<<<(N * 128 + 255) / 256, 256, 0, stream>>>(x, xb, N * 128);
    transT_bf16_kernel<<<(128 * 256 + 255) / 256, 256, 0, stream>>>(W0, w0t, 128, 256);
    transT_bf16_kernel<<<(256 * 256 + 255) / 256, 256, 0, stream>>>(W1, w1t, 256, 256);
    transT_bf16_kernel<<<(256 * 32 + 255) / 256, 256, 0, stream>>>(W2, w2t, 256, 32);

    const int MB = (N + 127) / 128;

    // layer 0: K=128
    gemm_bf16_1t<128, 128, 64, 64><<<dim3(2, MB), 256, 0, stream>>>(xb, w0t, hb, N, 256, 128);
    al_bf16<8, 32><<<(N * 8 + 255) / 256, 256, 0, stream>>>(hb, a_s0, a_d0, als, ald, N);
    gat_agg_w8<<<(N + 3) / 4, 256, 0, stream>>>(hb, als, ald, rowptr, colA, b0, g0, N);

    // layer 1: K=256
    gemm_bf16_1t<128, 128, 64, 64><<<dim3(2, MB), 256, 0, stream>>>(g0, w1t, hb, N, 256, 256);
    al_bf16<8, 32><<<(N * 8 + 255) / 256, 256, 0, stream>>>(hb, a_s1, a_d1, als, ald, N);
    gat_agg_w8<<<(N + 3) / 4, 256, 0, stream>>>(hb, als, ald, rowptr, colA, b1, g0, N);

    // layer 2: heads=1, C=32, K=256
    gemm_bf16_1t<128, 32, 32, 32><<<dim3(1, MB), 256, 0, stream>>>(g0, w2t, hb, N, 32, 256);
    al_bf16<1, 32><<<(N + 255) / 256, 256, 0, stream>>>(hb, a_s2, a_d2, als, ald, N);
    gat_agg_h1w<<<(N + 3) / 4, 256, 0, stream>>>(hb, als, ald, rowptr, colA, b2, out2, N);

    // fused pool + head
    pool_final_kernel<<<G, 256, 0, stream>>>(out2, gstart, lin_w, lin_b, (float*)d_out);
}

// Round 12
// 612.760 us; speedup vs baseline: 1.1322x; 1.0444x over previous
//
#include <hip/hip_runtime.h>
#include <hip/hip_bf16.h>

// ---------------------------------------------------------------------------
// GAT (3 layers) + global mean pool + linear head.
// R12: al fused into GEMM epilogue (f32 accumulators dotted with a_src/a_dst
// + 16-lane shfl reduce — removes 3 al kernels + 77 MB h re-reads); prep
// kernels merged; gstart folded into scan. agg8 at its measured ~3.8 TB/s
// L2-miss-path floor (R7-R11 invariant).
// ---------------------------------------------------------------------------

#define LRELU(x) ((x) >= 0.f ? (x) : 0.2f * (x))

typedef unsigned short ushort8 __attribute__((ext_vector_type(8)));
typedef unsigned short ushort4v __attribute__((ext_vector_type(4)));
typedef __attribute__((ext_vector_type(8))) short bf16x8;
typedef __attribute__((ext_vector_type(4))) float f32x4;

__device__ __forceinline__ float bf2f(unsigned short u) {
    return __uint_as_float(((unsigned)u) << 16);
}
__device__ __forceinline__ unsigned short f2bf(float f) {
    __hip_bfloat16 b = __float2bfloat16(f);
    return *reinterpret_cast<unsigned short*>(&b);
}
__device__ __forceinline__ void gl_lds16(const unsigned short* g, unsigned short* l) {
    __builtin_amdgcn_global_load_lds((const __attribute__((address_space(1))) void*)g,
                                     (__attribute__((address_space(3))) void*)l, 16, 0, 0);
}

// ---------------- CSR build ----------------

__global__ void deg_kernel(const int* __restrict__ dst, int* __restrict__ deg,
                           int E, int N) {
    int i = blockIdx.x * blockDim.x + threadIdx.x;
    if (i < E) atomicAdd(&deg[dst[i]], 1);
    else if (i < E + N) atomicAdd(&deg[i - E], 1);   // self loop
}

// scan + gstart (fused): block 0 does the rowptr scan with 1024 threads;
// threads <= G also binary-search the sorted batch for graph offsets.
__global__ void scan_kernel(const int* __restrict__ deg, int* __restrict__ rowptr, int n,
                            const int* __restrict__ batch, int* __restrict__ gstart,
                            int N, int G) {
    const int tid = threadIdx.x;
    if (tid <= G) {
        int lo = 0, hi = N;
        while (lo < hi) { int mid = (lo + hi) >> 1; if (batch[mid] < tid) lo = mid + 1; else hi = mid; }
        gstart[tid] = lo;
    }
    __shared__ int partial[1024];
    const int chunk = (n + 1023) / 1024;
    const int start = min(tid * chunk, n);
    const int end = min(start + chunk, n);
    int s = 0;
    for (int i = start; i < end; i++) s += deg[i];
    partial[tid] = s;
    __syncthreads();
    for (int o = 1; o < 1024; o <<= 1) {
        int v = (tid >= o) ? partial[tid - o] : 0;
        __syncthreads();
        partial[tid] += v;
        __syncthreads();
    }
    int run = (tid == 0) ? 0 : partial[tid - 1];
    for (int i = start; i < end; i++) { rowptr[i] = run; run += deg[i]; }
    if (tid == 0) rowptr[n] = partial[1023];
}

// Binned scatter on rowptr itself: after both passes rowptr[n] = END of
// segment n (start = rowptr[n-1], 0 for n=0) — shifted convention.
__global__ void scatter_col_binned(const int* __restrict__ src, const int* __restrict__ dst,
                                   int* __restrict__ rowptr, int* __restrict__ col,
                                   int E, int N, int lo, int hi) {
    int i = blockIdx.x * blockDim.x + threadIdx.x;
    if (i < E) {
        int d = dst[i];
        if (d < lo || d >= hi) return;
        int pos = atomicAdd(&rowptr[d], 1);
        col[pos] = src[i];
    } else if (i < E + N) {
        int d = i - E;
        if (d < lo || d >= hi) return;
        int pos = atomicAdd(&rowptr[d], 1);
        col[pos] = d;
    }
}

// ---------------- fused prep: x->bf16, W0/W1/W2 -> transposed bf16 ----------------

__global__ void prep_kernel(const float* __restrict__ x, const float* __restrict__ W0,
                            const float* __restrict__ W1, const float* __restrict__ W2,
                            unsigned short* __restrict__ xb, unsigned short* __restrict__ w0t,
                            unsigned short* __restrict__ w1t, unsigned short* __restrict__ w2t,
                            int N) {
    int i = blockIdx.x * blockDim.x + threadIdx.x;
    int nx = N * 128;
    if (i < nx) { xb[i] = f2bf(x[i]); return; }
    i -= nx;
    if (i < 256 * 128) {                          // W0 [128][256] -> w0t [256][128]
        int n = i / 128, k = i - n * 128;
        w0t[i] = f2bf(W0[(size_t)k * 256 + n]);
        return;
    }
    i -= 256 * 128;
    if (i < 256 * 256) {                          // W1 [256][256] -> w1t [256][256]
        int n = i / 256, k = i - n * 256;
        w1t[i] = f2bf(W1[(size_t)k * 256 + n]);
        return;
    }
    i -= 256 * 256;
    if (i < 32 * 256) {                           // W2 [256][32] -> w2t [32][256]
        int n = i / 256, k = i - n * 256;
        w2t[i] = f2bf(W2[(size_t)k * 32 + n]);
    }
}

// ---------------- plain-bf16 MFMA GEMM + fused attention logits ----------------
// C[M,Nn](bf16) = A[M,K](bf16) @ B[K,Nn], B transposed [Nn][K] bf16.
// Epilogue also computes als/ald: each head's 32 cols live inside one wave's
// 16-lane group span, so per (row, head) the dot is 8 FMAs + 4 shfl_xor.

template <int BM, int BN, int WM, int WN, int H>
__global__ __launch_bounds__(256)
void gemm_bf16_al(const unsigned short* __restrict__ A, const unsigned short* __restrict__ Bt,
                  unsigned short* __restrict__ Cc,
                  const float* __restrict__ a_src, const float* __restrict__ a_dst,
                  float* __restrict__ als, float* __restrict__ ald,
                  int M, int Nn, int K) {
    constexpr int BK = 64;
    constexpr int MT = WM / 16, NT = WN / 16;
    constexpr int NWX = BN / WN;
    constexpr int NHL = WN / 32;                  // heads per wave span
    __shared__ __attribute__((aligned(16))) unsigned short Ab[BM][BK];
    __shared__ __attribute__((aligned(16))) unsigned short Bb[BN][BK];
    const int tid = threadIdx.x;
    const int lane = tid & 63;
    const int wave = tid >> 6;
    const int wx = wave % NWX, wy = wave / NWX;
    const int by = blockIdx.y * BM;
    const int bx = blockIdx.x * BN;
    const int r16 = lane & 15, kg = lane >> 4;
    const int srow = lane >> 3, sslot = lane & 7;

    f32x4 acc[MT][NT];
#pragma unroll
    for (int i = 0; i < MT; i++)
#pragma unroll
        for (int j = 0; j < NT; j++) acc[i][j] = (f32x4){0.f, 0.f, 0.f, 0.f};

    for (int k0 = 0; k0 < K; k0 += BK) {
        for (int t = wave; t < BM / 8; t += 4) {
            int gm = by + t * 8 + srow;
            if (gm >= M) gm = M - 1;              // clamp: garbage lands in unstored rows
            gl_lds16(A + (size_t)gm * K + k0 + sslot * 8, &Ab[t * 8][0]);
        }
        for (int t = wave; t < BN / 8; t += 4) {
            int gn = bx + t * 8 + srow;
            gl_lds16(Bt + (size_t)gn * K + k0 + sslot * 8, &Bb[t * 8][0]);
        }
        __syncthreads();
#pragma unroll
        for (int ks = 0; ks < 2; ks++) {
            bf16x8 bh[NT];
#pragma unroll
            for (int j = 0; j < NT; j++)
                bh[j] = *(const bf16x8*)&Bb[wx * WN + j * 16 + r16][ks * 32 + kg * 8];
#pragma unroll
            for (int i = 0; i < MT; i++) {
                bf16x8 ah = *(const bf16x8*)&Ab[wy * WM + i * 16 + r16][ks * 32 + kg * 8];
#pragma unroll
                for (int j = 0; j < NT; j++)
                    acc[i][j] = __builtin_amdgcn_mfma_f32_16x16x32_bf16(ah, bh[j], acc[i][j], 0, 0, 0);
            }
        }
        __syncthreads();
    }

    // epilogue: C store (D row = (lane>>4)*4+reg, col = lane&15; m89-verified)
    // + fused als/ald.
    const int c0 = bx + wx * WN;
#pragma unroll
    for (int i = 0; i < MT; i++) {
#pragma unroll
        for (int r = 0; r < 4; r++) {
            int gm = by + wy * WM + i * 16 + kg * 4 + r;
            bool ok = gm < M;
            float sa[NHL] = {};
            float sd[NHL] = {};
#pragma unroll
            for (int j = 0; j < NT; j++) {
                int gn = c0 + j * 16 + r16;
                float v = acc[i][j][r];
                if (ok) Cc[(size_t)gm * Nn + gn] = f2bf(v);
                sa[j >> 1] += v * a_src[gn];
                sd[j >> 1] += v * a_dst[gn];
            }
#pragma unroll
            for (int m = 1; m < 16; m <<= 1) {
#pragma unroll
                for (int t = 0; t < NHL; t++) {
                    sa[t] += __shfl_xor(sa[t], m);
                    sd[t] += __shfl_xor(sd[t], m);
                }
            }
            if (ok && r16 == 0) {
#pragma unroll
                for (int t = 0; t < NHL; t++) {
                    int hh = (c0 >> 5) + t;
                    als[(size_t)gm * H + hh] = sa[t];
                    ald[(size_t)gm * H + hh] = sd[t];
                }
            }
        }
    }
}

// ---------------- H=8 aggregate: wave-per-node, fused edge weights ----------------

__global__ __launch_bounds__(256)
void gat_agg_w8(const unsigned short* __restrict__ hfeat,
                const float* __restrict__ als, const float* __restrict__ ald,
                const int* __restrict__ rowptr,           // shifted: rowptr[n] = END
                const int* __restrict__ col,
                const float* __restrict__ bias,
                unsigned short* __restrict__ outH,
                int N) {
    constexpr int CAP = 128;
    const int wid = threadIdx.x >> 6;
    const int lane = threadIdx.x & 63;
    const int n = blockIdx.x * 4 + wid;
    __shared__ float se_all[4][CAP * 8];
    __shared__ int scol_all[4][CAP];
    if (n >= N) return;
    float* se = se_all[wid];
    int* scol = scol_all[wid];

    const int r0 = (n == 0) ? 0 : rowptr[n - 1];
    const int deg = rowptr[n] - r0;
    const int dcap = min(deg, CAP);

    // stage col -> LDS (coalesced; same wave reads below, no barrier needed)
    for (int j = lane; j < dcap; j += 64) scol[j] = col[r0 + j];

    // ---- pass A: fused weights; slot = lane>>3 (edge), h = lane&7 (head) ----
    const int slot = lane >> 3, h = lane & 7;
    const float aldh = ald[(size_t)n * 8 + h];
    float psum = 0.f;
    for (int j = 0; j < deg; j += 8) {
        int e = j + slot;
        if (e < deg) {
            int s = (e < dcap) ? scol[e] : col[r0 + e];
            float ev = als[(size_t)s * 8 + h] + aldh;
            ev = LRELU(ev);
            float w = __expf(ev);
            psum += w;
            if (e < CAP) se[e * 8 + h] = w;
        }
    }
#pragma unroll
    for (int m = 8; m < 64; m <<= 1) psum += __shfl_xor(psum, m);
    const int q = lane >> 3;                 // this lane's head in pass B
    const float sinv = 1.0f / __shfl(psum, q);
    const float aldq = ald[(size_t)n * 8 + q];

    // ---- pass B: 4-deep gather ----
    const int cb = lane * 4;
    float a0 = 0.f, a1 = 0.f, a2 = 0.f, a3 = 0.f;
    int j = 0;
    for (; j + 3 < dcap; j += 4) {
        int s0 = __builtin_amdgcn_readfirstlane(scol[j]);
        int s1 = __builtin_amdgcn_readfirstlane(scol[j + 1]);
        int s2 = __builtin_amdgcn_readfirstlane(scol[j + 2]);
        int s3 = __builtin_amdgcn_readfirstlane(scol[j + 3]);
        ushort4v v0 = *(const ushort4v*)(hfeat + (size_t)s0 * 256 + cb);
        ushort4v v1 = *(const ushort4v*)(hfeat + (size_t)s1 * 256 + cb);
        ushort4v v2 = *(const ushort4v*)(hfeat + (size_t)s2 * 256 + cb);
        ushort4v v3 = *(const ushort4v*)(hfeat + (size_t)s3 * 256 + cb);
        float w0 = se[j * 8 + q];
        float w1 = se[j * 8 + 8 + q];
        float w2 = se[j * 8 + 16 + q];
        float w3 = se[j * 8 + 24 + q];
        a0 += bf2f(v0[0]) * w0; a1 += bf2f(v0[1]) * w0; a2 += bf2f(v0[2]) * w0; a3 += bf2f(v0[3]) * w0;
        a0 += bf2f(v1[0]) * w1; a1 += bf2f(v1[1]) * w1; a2 += bf2f(v1[2]) * w1; a3 += bf2f(v1[3]) * w1;
        a0 += bf2f(v2[0]) * w2; a1 += bf2f(v2[1]) * w2; a2 += bf2f(v2[2]) * w2; a3 += bf2f(v2[3]) * w2;
        a0 += bf2f(v3[0]) * w3; a1 += bf2f(v3[1]) * w3; a2 += bf2f(v3[2]) * w3; a3 += bf2f(v3[3]) * w3;
    }
    for (; j < dcap; j++) {
        int s0 = __builtin_amdgcn_readfirstlane(scol[j]);
        ushort4v v0 = *(const ushort4v*)(hfeat + (size_t)s0 * 256 + cb);
        float w0 = se[j * 8 + q];
        a0 += bf2f(v0[0]) * w0; a1 += bf2f(v0[1]) * w0; a2 += bf2f(v0[2]) * w0; a3 += bf2f(v0[3]) * w0;
    }
    for (; j < deg; j++) {                   // deg > CAP fallback (essentially never)
        int s0 = col[r0 + j];
        float ev = als[(size_t)s0 * 8 + q] + aldq;
        ev = LRELU(ev);
        float w0 = __expf(ev);
        ushort4v v0 = *(const ushort4v*)(hfeat + (size_t)s0 * 256 + cb);
        a0 += bf2f(v0[0]) * w0; a1 += bf2f(v0[1]) * w0; a2 += bf2f(v0[2]) * w0; a3 += bf2f(v0[3]) * w0;
    }

    // ---- epilogue: normalize + bias + relu + bf16 store ----
    float4 b4 = *(const float4*)&bias[cb];
    float o0 = fmaxf(a0 * sinv + b4.x, 0.f);
    float o1 = fmaxf(a1 * sinv + b4.y, 0.f);
    float o2 = fmaxf(a2 * sinv + b4.z, 0.f);
    float o3 = fmaxf(a3 * sinv + b4.w, 0.f);
    const size_t ob = (size_t)n * 256 + cb;
    *(ushort4v*)&outH[ob] = (ushort4v){f2bf(o0), f2bf(o1), f2bf(o2), f2bf(o3)};
}

// ---------------- H=1 aggregate: wave-per-node, fused weights ----------------

__global__ __launch_bounds__(256)
void gat_agg_h1w(const unsigned short* __restrict__ hfeat,
                 const float* __restrict__ als, const float* __restrict__ ald,
                 const int* __restrict__ rowptr, const int* __restrict__ col,
                 const float* __restrict__ bias, float* __restrict__ out, int N) {
    constexpr int CAP = 256;
    const int wid = threadIdx.x >> 6;
    const int lane = threadIdx.x & 63;
    const int n = blockIdx.x * 4 + wid;
    __shared__ float sw_all[4][CAP];
    __shared__ int scol_all[4][CAP];
    if (n >= N) return;
    float* sw = sw_all[wid];
    int* scol = scol_all[wid];

    const int r0 = (n == 0) ? 0 : rowptr[n - 1];
    const int deg = rowptr[n] - r0;
    const int dcap = min(deg, CAP);
    const float aldn = ald[n];

    float lsum = 0.f;
    for (int idx = lane; idx < deg; idx += 64) {
        int s = col[r0 + idx];
        float ev = als[s] + aldn;
        ev = LRELU(ev);
        float w = __expf(ev);
        if (idx < CAP) { sw[idx] = w; scol[idx] = s; }
        lsum += w;
    }
#pragma unroll
    for (int m = 1; m < 64; m <<= 1) lsum += __shfl_xor(lsum, m);
    const float sinv = 1.0f / lsum;

    const int slot = lane >> 3, ch = lane & 7;
    float a0 = 0.f, a1 = 0.f, a2 = 0.f, a3 = 0.f;
    for (int j = 0; j < dcap; j += 8) {
        int e = j + slot;
        int ec = min(e, dcap - 1);
        int s = scol[ec];
        float w = (e < dcap) ? sw[ec] : 0.f;
        ushort4v v = *(const ushort4v*)(hfeat + (size_t)s * 32 + ch * 4);
        a0 += bf2f(v[0]) * w; a1 += bf2f(v[1]) * w;
        a2 += bf2f(v[2]) * w; a3 += bf2f(v[3]) * w;
    }
    for (int j = CAP; j < deg; j += 8) {     // deg > CAP fallback
        int e = j + slot;
        int ec = min(e, deg - 1);
        int s = col[r0 + ec];
        float w = 0.f;
        if (e < deg) {
            float ev = als[s] + aldn;
            ev = LRELU(ev);
            w = __expf(ev);
        }
        ushort4v v = *(const ushort4v*)(hfeat + (size_t)s * 32 + ch * 4);
        a0 += bf2f(v[0]) * w; a1 += bf2f(v[1]) * w;
        a2 += bf2f(v[2]) * w; a3 += bf2f(v[3]) * w;
    }
#pragma unroll
    for (int m = 8; m < 64; m <<= 1) {
        a0 += __shfl_xor(a0, m);
        a1 += __shfl_xor(a1, m);
        a2 += __shfl_xor(a2, m);
        a3 += __shfl_xor(a3, m);
    }
    if (slot == 0) {
        float4 b4 = *(const float4*)&bias[ch * 4];
        float4 o;
        o.x = a0 * sinv + b4.x;
        o.y = a1 * sinv + b4.y;
        o.z = a2 * sinv + b4.z;
        o.w = a3 * sinv + b4.w;
        *(float4*)&out[(size_t)n * 32 + ch * 4] = o;
    }
}

// ---------------- fused pool + head (sorted batch, no atomics) ----------------

__global__ __launch_bounds__(256)
void pool_final_kernel(const float* __restrict__ h, const int* __restrict__ gstart,
                       const float* __restrict__ lin_w, const float* __restrict__ lin_b,
                       float* __restrict__ out) {
    const int g = blockIdx.x;
    const int tid = threadIdx.x;
    const int n0 = gstart[g], n1 = gstart[g + 1];
    const int r = tid >> 5, c = tid & 31;
    __shared__ float pp[4][32];
    __shared__ float pm[32];
    float acc = 0.f;
    for (int n = n0 + r; n < n1; n += 8) acc += h[(size_t)n * 32 + c];
    acc += __shfl_xor(acc, 32);
    if ((tid & 63) < 32) pp[tid >> 6][c] = acc;
    __syncthreads();
    if (tid < 32) {
        float s = pp[0][tid] + pp[1][tid] + pp[2][tid] + pp[3][tid];
        pm[tid] = s / fmaxf((float)(n1 - n0), 1.f);
    }
    __syncthreads();
    if (tid < 64) {
        float a = lin_b[tid];
#pragma unroll 8
        for (int cc = 0; cc < 32; cc++) a += pm[cc] * lin_w[cc * 64 + tid];
        out[(size_t)g * 64 + tid] = a;
    }
}

// ---------------- launch ----------------

extern "C" void kernel_launch(void* const* d_in, const int* in_sizes, int n_in,
                              void* d_out, int out_size, void* d_ws, size_t ws_size,
                              hipStream_t stream) {
    const float* x     = (const float*)d_in[0];
    const int*   ei    = (const int*)d_in[1];
    const int*   batch = (const int*)d_in[2];
    const float* W0    = (const float*)d_in[3];
    const float* a_s0  = (const float*)d_in[4];
    const float* a_d0  = (const float*)d_in[5];
    const float* b0    = (const float*)d_in[6];
    const float* W1    = (const float*)d_in[7];
    const float* a_s1  = (const float*)d_in[8];
    const float* a_d1  = (const float*)d_in[9];
    const float* b1    = (const float*)d_in[10];
    const float* W2    = (const float*)d_in[11];
    const float* a_s2  = (const float*)d_in[12];
    const float* a_d2  = (const float*)d_in[13];
    const float* b2    = (const float*)d_in[14];
    const float* lin_w = (const float*)d_in[15];
    const float* lin_b = (const float*)d_in[16];

    const int N = in_sizes[0] / 128;   // 50000
    const int E = in_sizes[1] / 2;     // 1600000
    const int G = 256;
    const int Etot = E + N;
    const int* src = ei;
    const int* dst = ei + E;

    char* w = (char*)d_ws;
    size_t off = 0;
    auto alloc = [&](size_t bytes) -> void* {
        void* p = (void*)(w + off);
        off += (bytes + 255) & ~(size_t)255;
        return p;
    };
    int* deg    = (int*)alloc((size_t)N * 4);
    int* rowptr = (int*)alloc((size_t)(N + 1) * 4);
    int* colA   = (int*)alloc((size_t)Etot * 4);
    int* gstart = (int*)alloc((size_t)(G + 1) * 4);
    float* als  = (float*)alloc((size_t)N * 8 * 4);
    float* ald  = (float*)alloc((size_t)N * 8 * 4);
    unsigned short* hb  = (unsigned short*)alloc((size_t)N * 256 * 2);   // GEMM output
    unsigned short* g0  = (unsigned short*)alloc((size_t)N * 256 * 2);   // agg output
    float* out2 = (float*)alloc((size_t)N * 32 * 4);
    unsigned short* w0t = (unsigned short*)alloc((size_t)256 * 128 * 2); // W0^T bf16
    unsigned short* w1t = (unsigned short*)alloc((size_t)256 * 256 * 2);
    unsigned short* w2t = (unsigned short*)alloc((size_t)32 * 256 * 2);
    unsigned short* xb = g0;                        // x bf16, aliased (dead before agg0 writes g0)

    hipMemsetAsync(deg, 0, (size_t)N * 4, stream);

    // CSR (shifted convention after scatter) + graph offsets
    deg_kernel<<<(Etot + 255) / 256, 256, 0, stream>>>(dst, deg, E, N);
    scan_kernel<<<1, 1024, 0, stream>>>(deg, rowptr, N, batch, gstart, N, G);
    for (int p = 0; p < 2; p++) {
        int lo = (int)((size_t)N * p / 2);
        int hi = (int)((size_t)N * (p + 1) / 2);
        scatter_col_binned<<<(Etot + 255) / 256, 256, 0, stream>>>(src, dst, rowptr, colA, E, N, lo, hi);
    }

    // fused prep (x round + 3 weight transposes)
    {
        long long tot = (long long)N * 128 + 256 * 128 + 256 * 256 + 32 * 256;
        prep_kernel<<<(int)((tot + 255) / 256), 256, 0, stream>>>(x, W0, W1, W2, xb, w0t, w1t, w2t, N);
    }

    const int MB = (N + 127) / 128;

    // layer 0: K=128 (al fused into GEMM epilogue)
    gemm_bf16_al<128, 128, 64, 64, 8><<<dim3(2, MB), 256, 0, stream>>>(
        xb, w0t, hb, a_s0, a_d0, als, ald, N, 256, 128);
    gat_agg_w8<<<(N + 3) / 4, 256, 0, stream>>>(hb, als, ald, rowptr, colA, b0, g0, N);

    // layer 1: K=256
    gemm_bf16_al<128, 128, 64, 64, 8><<<dim3(2, MB), 256, 0, stream>>>(
        g0, w1t, hb, a_s1, a_d1, als, ald, N, 256, 256);
    gat_agg_w8<<<(N + 3) / 4, 256, 0, stream>>>(hb, als, ald, rowptr, colA, b1, g0, N);

    // layer 2: heads=1, C=32, K=256
    gemm_bf16_al<128, 32, 32, 32, 1><<<dim3(1, MB), 256, 0, stream>>>(
        g0, w2t, hb, a_s2, a_d2, als, ald, N, 32, 256);
    gat_agg_h1w<<<(N + 3) / 4, 256, 0, stream>>>(hb, als, ald, rowptr, colA, b2, out2, N);

    // fused pool + head
    pool_final_kernel<<<G, 256, 0, stream>>>(out2, gstart, lin_w, lin_b, (float*)d_out);
}

// Round 13
// 580.368 us; speedup vs baseline: 1.1953x; 1.0558x over previous
//
#include <hip/hip_runtime.h>
#include <hip/hip_bf16.h>

// ---------------------------------------------------------------------------
// GAT (3 layers) + global mean pool + linear head.
// R13: block-range fusion of independent kernels — (deg ∥ prep) and
// (gemm0 ∥ 4-bin scatter) share one launch each; complementary pipes overlap
// (MFMA-bound GEMM vs latency-bound scatter). agg8 at its measured
// ~3.8 TB/s random-gather floor (R7-R12 invariant).
// ---------------------------------------------------------------------------

#define LRELU(x) ((x) >= 0.f ? (x) : 0.2f * (x))

typedef unsigned short ushort8 __attribute__((ext_vector_type(8)));
typedef unsigned short ushort4v __attribute__((ext_vector_type(4)));
typedef __attribute__((ext_vector_type(8))) short bf16x8;
typedef __attribute__((ext_vector_type(4))) float f32x4;

__device__ __forceinline__ float bf2f(unsigned short u) {
    return __uint_as_float(((unsigned)u) << 16);
}
__device__ __forceinline__ unsigned short f2bf(float f) {
    __hip_bfloat16 b = __float2bfloat16(f);
    return *reinterpret_cast<unsigned short*>(&b);
}
__device__ __forceinline__ void gl_lds16(const unsigned short* g, unsigned short* l) {
    __builtin_amdgcn_global_load_lds((const __attribute__((address_space(1))) void*)g,
                                     (__attribute__((address_space(3))) void*)l, 16, 0, 0);
}

// ---------------- GEMM core (shared by standalone + mega kernels) ----------------
// C[M,Nn](bf16) = A[M,K](bf16) @ B[K,Nn], B transposed [Nn][K] bf16.
// Epilogue fuses attention logits (als/ald) via 16-lane shfl reduce.
// D layout: row = (lane>>4)*4 + reg, col = lane&15 (m89-verified, R5+ passed).

template <int BM, int BN, int WM, int WN, int H>
__device__ __forceinline__
void gemm_core(unsigned short* __restrict__ Ab, unsigned short* __restrict__ Bb,
               const unsigned short* __restrict__ A, const unsigned short* __restrict__ Bt,
               unsigned short* __restrict__ Cc,
               const float* __restrict__ a_src, const float* __restrict__ a_dst,
               float* __restrict__ als, float* __restrict__ ald,
               int M, int Nn, int K, int bxi, int byi) {
    constexpr int BK = 64;
    constexpr int MT = WM / 16, NT = WN / 16;
    constexpr int NWX = BN / WN;
    constexpr int NHL = WN / 32;
    const int tid = threadIdx.x;
    const int lane = tid & 63;
    const int wave = tid >> 6;
    const int wx = wave % NWX, wy = wave / NWX;
    const int by = byi * BM;
    const int bx = bxi * BN;
    const int r16 = lane & 15, kg = lane >> 4;
    const int srow = lane >> 3, sslot = lane & 7;

    f32x4 acc[MT][NT];
#pragma unroll
    for (int i = 0; i < MT; i++)
#pragma unroll
        for (int j = 0; j < NT; j++) acc[i][j] = (f32x4){0.f, 0.f, 0.f, 0.f};

    for (int k0 = 0; k0 < K; k0 += BK) {
        for (int t = wave; t < BM / 8; t += 4) {
            int gm = by + t * 8 + srow;
            if (gm >= M) gm = M - 1;              // clamp: garbage lands in unstored rows
            gl_lds16(A + (size_t)gm * K + k0 + sslot * 8, Ab + (t * 8) * BK);
        }
        for (int t = wave; t < BN / 8; t += 4) {
            int gn = bx + t * 8 + srow;
            gl_lds16(Bt + (size_t)gn * K + k0 + sslot * 8, Bb + (t * 8) * BK);
        }
        __syncthreads();
#pragma unroll
        for (int ks = 0; ks < 2; ks++) {
            bf16x8 bh[NT];
#pragma unroll
            for (int j = 0; j < NT; j++)
                bh[j] = *(const bf16x8*)(Bb + (wx * WN + j * 16 + r16) * BK + ks * 32 + kg * 8);
#pragma unroll
            for (int i = 0; i < MT; i++) {
                bf16x8 ah = *(const bf16x8*)(Ab + (wy * WM + i * 16 + r16) * BK + ks * 32 + kg * 8);
#pragma unroll
                for (int j = 0; j < NT; j++)
                    acc[i][j] = __builtin_amdgcn_mfma_f32_16x16x32_bf16(ah, bh[j], acc[i][j], 0, 0, 0);
            }
        }
        __syncthreads();
    }

    const int c0 = bx + wx * WN;
#pragma unroll
    for (int i = 0; i < MT; i++) {
#pragma unroll
        for (int r = 0; r < 4; r++) {
            int gm = by + wy * WM + i * 16 + kg * 4 + r;
            bool ok = gm < M;
            float sa[NHL] = {};
            float sd[NHL] = {};
#pragma unroll
            for (int j = 0; j < NT; j++) {
                int gn = c0 + j * 16 + r16;
                float v = acc[i][j][r];
                if (ok) Cc[(size_t)gm * Nn + gn] = f2bf(v);
                sa[j >> 1] += v * a_src[gn];
                sd[j >> 1] += v * a_dst[gn];
            }
#pragma unroll
            for (int m = 1; m < 16; m <<= 1) {
#pragma unroll
                for (int t = 0; t < NHL; t++) {
                    sa[t] += __shfl_xor(sa[t], m);
                    sd[t] += __shfl_xor(sd[t], m);
                }
            }
            if (ok && r16 == 0) {
#pragma unroll
                for (int t = 0; t < NHL; t++) {
                    int hh = (c0 >> 5) + t;
                    als[(size_t)gm * H + hh] = sa[t];
                    ald[(size_t)gm * H + hh] = sd[t];
                }
            }
        }
    }
}

// ---------------- deg ∥ prep (block-range fused) ----------------

__global__ __launch_bounds__(256)
void deg_prep_kernel(const int* __restrict__ dst, int* __restrict__ deg, int E, int N,
                     const float* __restrict__ x, const float* __restrict__ W0,
                     const float* __restrict__ W1, const float* __restrict__ W2,
                     unsigned short* __restrict__ xb, unsigned short* __restrict__ w0t,
                     unsigned short* __restrict__ w1t, unsigned short* __restrict__ w2t,
                     int DEG_BLKS) {
    if ((int)blockIdx.x < DEG_BLKS) {
        int i = blockIdx.x * 256 + threadIdx.x;
        if (i < E) atomicAdd(&deg[dst[i]], 1);
        else if (i < E + N) atomicAdd(&deg[i - E], 1);   // self loop
        return;
    }
    int i = (blockIdx.x - DEG_BLKS) * 256 + threadIdx.x;
    int nx = N * 128;
    if (i < nx) { xb[i] = f2bf(x[i]); return; }
    i -= nx;
    if (i < 256 * 128) {                          // W0 [128][256] -> w0t [256][128]
        int n = i / 128, k = i - n * 128;
        w0t[i] = f2bf(W0[(size_t)k * 256 + n]);
        return;
    }
    i -= 256 * 128;
    if (i < 256 * 256) {                          // W1 [256][256] -> w1t [256][256]
        int n = i / 256, k = i - n * 256;
        w1t[i] = f2bf(W1[(size_t)k * 256 + n]);
        return;
    }
    i -= 256 * 256;
    if (i < 32 * 256) {                           // W2 [256][32] -> w2t [32][256]
        int n = i / 256, k = i - n * 256;
        w2t[i] = f2bf(W2[(size_t)k * 32 + n]);
    }
}

// ---------------- scan + gstart (fused, single block) ----------------

__global__ void scan_kernel(const int* __restrict__ deg, int* __restrict__ rowptr, int n,
                            const int* __restrict__ batch, int* __restrict__ gstart,
                            int N, int G) {
    const int tid = threadIdx.x;
    if (tid <= G) {
        int lo = 0, hi = N;
        while (lo < hi) { int mid = (lo + hi) >> 1; if (batch[mid] < tid) lo = mid + 1; else hi = mid; }
        gstart[tid] = lo;
    }
    __shared__ int partial[1024];
    const int chunk = (n + 1023) / 1024;
    const int start = min(tid * chunk, n);
    const int end = min(start + chunk, n);
    int s = 0;
    for (int i = start; i < end; i++) s += deg[i];
    partial[tid] = s;
    __syncthreads();
    for (int o = 1; o < 1024; o <<= 1) {
        int v = (tid >= o) ? partial[tid - o] : 0;
        __syncthreads();
        partial[tid] += v;
        __syncthreads();
    }
    int run = (tid == 0) ? 0 : partial[tid - 1];
    for (int i = start; i < end; i++) { rowptr[i] = run; run += deg[i]; }
    if (tid == 0) rowptr[n] = partial[1023];
}

// ---------------- mega0: gemm0(+al) ∥ 4-bin scatter ----------------
// gemm blocks first (heavy, MFMA-bound); scatter bins follow in block-ID
// order (~sequential since blocks/bin >> resident blocks), preserving the
// R6 write-locality. Bins write disjoint dst ranges -> order-independent.
// After all bins: rowptr[n] = END of segment n (shifted convention).

__global__ __launch_bounds__(256)
void mega0_kernel(const unsigned short* __restrict__ A, const unsigned short* __restrict__ Bt,
                  unsigned short* __restrict__ Cc,
                  const float* __restrict__ a_src, const float* __restrict__ a_dst,
                  float* __restrict__ als, float* __restrict__ ald, int M, int K,
                  const int* __restrict__ src, const int* __restrict__ dst,
                  int* __restrict__ rowptr, int* __restrict__ col, int E, int N,
                  int GEMM_BLKS, int SCAT_BLKS) {
    __shared__ __attribute__((aligned(16))) unsigned short Ab[128 * 64];
    __shared__ __attribute__((aligned(16))) unsigned short Bb[128 * 64];
    const int bid = blockIdx.x;
    if (bid < GEMM_BLKS) {
        gemm_core<128, 128, 64, 64, 8>(Ab, Bb, A, Bt, Cc, a_src, a_dst, als, ald,
                                       M, 256, K, bid & 1, bid >> 1);
        return;
    }
    const int sb = bid - GEMM_BLKS;
    const int bin = sb / SCAT_BLKS;
    const int i = (sb - bin * SCAT_BLKS) * 256 + threadIdx.x;
    const int lo = (int)((long long)N * bin / 4);
    const int hi = (int)((long long)N * (bin + 1) / 4);
    int s, d;
    if (i < E) { d = dst[i]; s = src[i]; }
    else if (i < E + N) { d = i - E; s = d; }
    else return;
    if (d < lo || d >= hi) return;
    int pos = atomicAdd(&rowptr[d], 1);
    col[pos] = s;
}

// ---------------- standalone GEMM (+al) for layers 1, 2 ----------------

template <int BM, int BN, int WM, int WN, int H>
__global__ __launch_bounds__(256)
void gemm_bf16_al(const unsigned short* __restrict__ A, const unsigned short* __restrict__ Bt,
                  unsigned short* __restrict__ Cc,
                  const float* __restrict__ a_src, const float* __restrict__ a_dst,
                  float* __restrict__ als, float* __restrict__ ald,
                  int M, int Nn, int K) {
    __shared__ __attribute__((aligned(16))) unsigned short Ab[BM * 64];
    __shared__ __attribute__((aligned(16))) unsigned short Bb[BN * 64];
    gemm_core<BM, BN, WM, WN, H>(Ab, Bb, A, Bt, Cc, a_src, a_dst, als, ald,
                                 M, Nn, K, blockIdx.x, blockIdx.y);
}

// ---------------- H=8 aggregate: wave-per-node, fused edge weights ----------------

__global__ __launch_bounds__(256)
void gat_agg_w8(const unsigned short* __restrict__ hfeat,
                const float* __restrict__ als, const float* __restrict__ ald,
                const int* __restrict__ rowptr,           // shifted: rowptr[n] = END
                const int* __restrict__ col,
                const float* __restrict__ bias,
                unsigned short* __restrict__ outH,
                int N) {
    constexpr int CAP = 128;
    const int wid = threadIdx.x >> 6;
    const int lane = threadIdx.x & 63;
    const int n = blockIdx.x * 4 + wid;
    __shared__ float se_all[4][CAP * 8];
    __shared__ int scol_all[4][CAP];
    if (n >= N) return;
    float* se = se_all[wid];
    int* scol = scol_all[wid];

    const int r0 = (n == 0) ? 0 : rowptr[n - 1];
    const int deg = rowptr[n] - r0;
    const int dcap = min(deg, CAP);

    // stage col -> LDS (coalesced; same wave reads below, no barrier needed)
    for (int j = lane; j < dcap; j += 64) scol[j] = col[r0 + j];

    // ---- pass A: fused weights; slot = lane>>3 (edge), h = lane&7 (head) ----
    const int slot = lane >> 3, h = lane & 7;
    const float aldh = ald[(size_t)n * 8 + h];
    float psum = 0.f;
    for (int j = 0; j < deg; j += 8) {
        int e = j + slot;
        if (e < deg) {
            int s = (e < dcap) ? scol[e] : col[r0 + e];
            float ev = als[(size_t)s * 8 + h] + aldh;
            ev = LRELU(ev);
            float w = __expf(ev);
            psum += w;
            if (e < CAP) se[e * 8 + h] = w;
        }
    }
#pragma unroll
    for (int m = 8; m < 64; m <<= 1) psum += __shfl_xor(psum, m);
    const int q = lane >> 3;                 // this lane's head in pass B
    const float sinv = 1.0f / __shfl(psum, q);
    const float aldq = ald[(size_t)n * 8 + q];

    // ---- pass B: 4-deep gather ----
    const int cb = lane * 4;
    float a0 = 0.f, a1 = 0.f, a2 = 0.f, a3 = 0.f;
    int j = 0;
    for (; j + 3 < dcap; j += 4) {
        int s0 = __builtin_amdgcn_readfirstlane(scol[j]);
        int s1 = __builtin_amdgcn_readfirstlane(scol[j + 1]);
        int s2 = __builtin_amdgcn_readfirstlane(scol[j + 2]);
        int s3 = __builtin_amdgcn_readfirstlane(scol[j + 3]);
        ushort4v v0 = *(const ushort4v*)(hfeat + (size_t)s0 * 256 + cb);
        ushort4v v1 = *(const ushort4v*)(hfeat + (size_t)s1 * 256 + cb);
        ushort4v v2 = *(const ushort4v*)(hfeat + (size_t)s2 * 256 + cb);
        ushort4v v3 = *(const ushort4v*)(hfeat + (size_t)s3 * 256 + cb);
        float w0 = se[j * 8 + q];
        float w1 = se[j * 8 + 8 + q];
        float w2 = se[j * 8 + 16 + q];
        float w3 = se[j * 8 + 24 + q];
        a0 += bf2f(v0[0]) * w0; a1 += bf2f(v0[1]) * w0; a2 += bf2f(v0[2]) * w0; a3 += bf2f(v0[3]) * w0;
        a0 += bf2f(v1[0]) * w1; a1 += bf2f(v1[1]) * w1; a2 += bf2f(v1[2]) * w1; a3 += bf2f(v1[3]) * w1;
        a0 += bf2f(v2[0]) * w2; a1 += bf2f(v2[1]) * w2; a2 += bf2f(v2[2]) * w2; a3 += bf2f(v2[3]) * w2;
        a0 += bf2f(v3[0]) * w3; a1 += bf2f(v3[1]) * w3; a2 += bf2f(v3[2]) * w3; a3 += bf2f(v3[3]) * w3;
    }
    for (; j < dcap; j++) {
        int s0 = __builtin_amdgcn_readfirstlane(scol[j]);
        ushort4v v0 = *(const ushort4v*)(hfeat + (size_t)s0 * 256 + cb);
        float w0 = se[j * 8 + q];
        a0 += bf2f(v0[0]) * w0; a1 += bf2f(v0[1]) * w0; a2 += bf2f(v0[2]) * w0; a3 += bf2f(v0[3]) * w0;
    }
    for (; j < deg; j++) {                   // deg > CAP fallback (essentially never)
        int s0 = col[r0 + j];
        float ev = als[(size_t)s0 * 8 + q] + aldq;
        ev = LRELU(ev);
        float w0 = __expf(ev);
        ushort4v v0 = *(const ushort4v*)(hfeat + (size_t)s0 * 256 + cb);
        a0 += bf2f(v0[0]) * w0; a1 += bf2f(v0[1]) * w0; a2 += bf2f(v0[2]) * w0; a3 += bf2f(v0[3]) * w0;
    }

    // ---- epilogue: normalize + bias + relu + bf16 store ----
    float4 b4 = *(const float4*)&bias[cb];
    float o0 = fmaxf(a0 * sinv + b4.x, 0.f);
    float o1 = fmaxf(a1 * sinv + b4.y, 0.f);
    float o2 = fmaxf(a2 * sinv + b4.z, 0.f);
    float o3 = fmaxf(a3 * sinv + b4.w, 0.f);
    const size_t ob = (size_t)n * 256 + cb;
    *(ushort4v*)&outH[ob] = (ushort4v){f2bf(o0), f2bf(o1), f2bf(o2), f2bf(o3)};
}

// ---------------- H=1 aggregate: wave-per-node, fused weights ----------------

__global__ __launch_bounds__(256)
void gat_agg_h1w(const unsigned short* __restrict__ hfeat,
                 const float* __restrict__ als, const float* __restrict__ ald,
                 const int* __restrict__ rowptr, const int* __restrict__ col,
                 const float* __restrict__ bias, float* __restrict__ out, int N) {
    constexpr int CAP = 256;
    const int wid = threadIdx.x >> 6;
    const int lane = threadIdx.x & 63;
    const int n = blockIdx.x * 4 + wid;
    __shared__ float sw_all[4][CAP];
    __shared__ int scol_all[4][CAP];
    if (n >= N) return;
    float* sw = sw_all[wid];
    int* scol = scol_all[wid];

    const int r0 = (n == 0) ? 0 : rowptr[n - 1];
    const int deg = rowptr[n] - r0;
    const int dcap = min(deg, CAP);
    const float aldn = ald[n];

    float lsum = 0.f;
    for (int idx = lane; idx < deg; idx += 64) {
        int s = col[r0 + idx];
        float ev = als[s] + aldn;
        ev = LRELU(ev);
        float w = __expf(ev);
        if (idx < CAP) { sw[idx] = w; scol[idx] = s; }
        lsum += w;
    }
#pragma unroll
    for (int m = 1; m < 64; m <<= 1) lsum += __shfl_xor(lsum, m);
    const float sinv = 1.0f / lsum;

    const int slot = lane >> 3, ch = lane & 7;
    float a0 = 0.f, a1 = 0.f, a2 = 0.f, a3 = 0.f;
    for (int j = 0; j < dcap; j += 8) {
        int e = j + slot;
        int ec = min(e, dcap - 1);
        int s = scol[ec];
        float w = (e < dcap) ? sw[ec] : 0.f;
        ushort4v v = *(const ushort4v*)(hfeat + (size_t)s * 32 + ch * 4);
        a0 += bf2f(v[0]) * w; a1 += bf2f(v[1]) * w;
        a2 += bf2f(v[2]) * w; a3 += bf2f(v[3]) * w;
    }
    for (int j = CAP; j < deg; j += 8) {     // deg > CAP fallback
        int e = j + slot;
        int ec = min(e, deg - 1);
        int s = col[r0 + ec];
        float w = 0.f;
        if (e < deg) {
            float ev = als[s] + aldn;
            ev = LRELU(ev);
            w = __expf(ev);
        }
        ushort4v v = *(const ushort4v*)(hfeat + (size_t)s * 32 + ch * 4);
        a0 += bf2f(v[0]) * w; a1 += bf2f(v[1]) * w;
        a2 += bf2f(v[2]) * w; a3 += bf2f(v[3]) * w;
    }
#pragma unroll
    for (int m = 8; m < 64; m <<= 1) {
        a0 += __shfl_xor(a0, m);
        a1 += __shfl_xor(a1, m);
        a2 += __shfl_xor(a2, m);
        a3 += __shfl_xor(a3, m);
    }
    if (slot == 0) {
        float4 b4 = *(const float4*)&bias[ch * 4];
        float4 o;
        o.x = a0 * sinv + b4.x;
        o.y = a1 * sinv + b4.y;
        o.z = a2 * sinv + b4.z;
        o.w = a3 * sinv + b4.w;
        *(float4*)&out[(size_t)n * 32 + ch * 4] = o;
    }
}

// ---------------- fused pool + head (sorted batch, no atomics) ----------------

__global__ __launch_bounds__(256)
void pool_final_kernel(const float* __restrict__ h, const int* __restrict__ gstart,
                       const float* __restrict__ lin_w, const float* __restrict__ lin_b,
                       float* __restrict__ out) {
    const int g = blockIdx.x;
    const int tid = threadIdx.x;
    const int n0 = gstart[g], n1 = gstart[g + 1];
    const int r = tid >> 5, c = tid & 31;
    __shared__ float pp[4][32];
    __shared__ float pm[32];
    float acc = 0.f;
    for (int n = n0 + r; n < n1; n += 8) acc += h[(size_t)n * 32 + c];
    acc += __shfl_xor(acc, 32);
    if ((tid & 63) < 32) pp[tid >> 6][c] = acc;
    __syncthreads();
    if (tid < 32) {
        float s = pp[0][tid] + pp[1][tid] + pp[2][tid] + pp[3][tid];
        pm[tid] = s / fmaxf((float)(n1 - n0), 1.f);
    }
    __syncthreads();
    if (tid < 64) {
        float a = lin_b[tid];
#pragma unroll 8
        for (int cc = 0; cc < 32; cc++) a += pm[cc] * lin_w[cc * 64 + tid];
        out[(size_t)g * 64 + tid] = a;
    }
}

// ---------------- launch ----------------

extern "C" void kernel_launch(void* const* d_in, const int* in_sizes, int n_in,
                              void* d_out, int out_size, void* d_ws, size_t ws_size,
                              hipStream_t stream) {
    const float* x     = (const float*)d_in[0];
    const int*   ei    = (const int*)d_in[1];
    const int*   batch = (const int*)d_in[2];
    const float* W0    = (const float*)d_in[3];
    const float* a_s0  = (const float*)d_in[4];
    const float* a_d0  = (const float*)d_in[5];
    const float* b0    = (const float*)d_in[6];
    const float* W1    = (const float*)d_in[7];
    const float* a_s1  = (const float*)d_in[8];
    const float* a_d1  = (const float*)d_in[9];
    const float* b1    = (const float*)d_in[10];
    const float* W2    = (const float*)d_in[11];
    const float* a_s2  = (const float*)d_in[12];
    const float* a_d2  = (const float*)d_in[13];
    const float* b2    = (const float*)d_in[14];
    const float* lin_w = (const float*)d_in[15];
    const float* lin_b = (const float*)d_in[16];

    const int N = in_sizes[0] / 128;   // 50000
    const int E = in_sizes[1] / 2;     // 1600000
    const int G = 256;
    const int Etot = E + N;
    const int* src = ei;
    const int* dst = ei + E;

    char* w = (char*)d_ws;
    size_t off = 0;
    auto alloc = [&](size_t bytes) -> void* {
        void* p = (void*)(w + off);
        off += (bytes + 255) & ~(size_t)255;
        return p;
    };
    int* deg    = (int*)alloc((size_t)N * 4);
    int* rowptr = (int*)alloc((size_t)(N + 1) * 4);
    int* colA   = (int*)alloc((size_t)Etot * 4);
    int* gstart = (int*)alloc((size_t)(G + 1) * 4);
    float* als  = (float*)alloc((size_t)N * 8 * 4);
    float* ald  = (float*)alloc((size_t)N * 8 * 4);
    unsigned short* hb  = (unsigned short*)alloc((size_t)N * 256 * 2);   // GEMM output
    unsigned short* g0  = (unsigned short*)alloc((size_t)N * 256 * 2);   // agg output
    float* out2 = (float*)alloc((size_t)N * 32 * 4);
    unsigned short* w0t = (unsigned short*)alloc((size_t)256 * 128 * 2); // W0^T bf16
    unsigned short* w1t = (unsigned short*)alloc((size_t)256 * 256 * 2);
    unsigned short* w2t = (unsigned short*)alloc((size_t)32 * 256 * 2);
    unsigned short* xb = g0;                        // x bf16, aliased (dead before agg0 writes g0)

    hipMemsetAsync(deg, 0, (size_t)N * 4, stream);

    // deg ∥ prep (independent; block-range fused)
    {
        const int DEG_BLKS = (Etot + 255) / 256;
        long long prep_elems = (long long)N * 128 + 256 * 128 + 256 * 256 + 32 * 256;
        const int PREP_BLKS = (int)((prep_elems + 255) / 256);
        deg_prep_kernel<<<DEG_BLKS + PREP_BLKS, 256, 0, stream>>>(
            dst, deg, E, N, x, W0, W1, W2, xb, w0t, w1t, w2t, DEG_BLKS);
    }

    // scan + gstart
    scan_kernel<<<1, 1024, 0, stream>>>(deg, rowptr, N, batch, gstart, N, G);

    const int MB = (N + 127) / 128;

    // gemm0(+al) ∥ 4-bin scatter (independent; agg0 needs both)
    {
        const int GEMM_BLKS = 2 * MB;
        const int SCAT_BLKS = (Etot + 255) / 256;
        mega0_kernel<<<GEMM_BLKS + 4 * SCAT_BLKS, 256, 0, stream>>>(
            xb, w0t, hb, a_s0, a_d0, als, ald, N, 128,
            src, dst, rowptr, colA, E, N, GEMM_BLKS, SCAT_BLKS);
    }
    gat_agg_w8<<<(N + 3) / 4, 256, 0, stream>>>(hb, als, ald, rowptr, colA, b0, g0, N);

    // layer 1: K=256
    gemm_bf16_al<128, 128, 64, 64, 8><<<dim3(2, MB), 256, 0, stream>>>(
        g0, w1t, hb, a_s1, a_d1, als, ald, N, 256, 256);
    gat_agg_w8<<<(N + 3) / 4, 256, 0, stream>>>(hb, als, ald, rowptr, colA, b1, g0, N);

    // layer 2: heads=1, C=32, K=256
    gemm_bf16_al<128, 32, 32, 32, 1><<<dim3(1, MB), 256, 0, stream>>>(
        g0, w2t, hb, a_s2, a_d2, als, ald, N, 32, 256);
    gat_agg_h1w<<<(N + 3) / 4, 256, 0, stream>>>(hb, als, ald, rowptr, colA, b2, out2, N);

    // fused pool + head
    pool_final_kernel<<<G, 256, 0, stream>>>(out2, gstart, lin_w, lin_b, (float*)d_out);
}